// Round 6
// baseline (934.456 us; speedup 1.0000x reference)
//
#include <hip/hip_runtime.h>
#include <hip/hip_bf16.h>
#include <math.h>
#include <stdint.h>

// Problem constants (deterministic from setup_inputs)
#define NB 32
#define NQ 300
#define ND 256
#define NH 8
#define HD 32
#define NL 4
#define NP 4
#define V_TOT 8500           // 6400+1600+400+100
#define BQ_TOT (NB*NQ)       // 9600
#define MVAL (NB*V_TOT)      // 272000
#define NOA 384              // fused off(256)+attn(128) cols

typedef short v8s __attribute__((ext_vector_type(8)));
typedef float v4f __attribute__((ext_vector_type(4)));

#define AS1 __attribute__((address_space(1)))
#define AS3 __attribute__((address_space(3)))

__device__ __forceinline__ void copy16_async(const void* g, void* l) {
#if __has_builtin(__builtin_amdgcn_global_load_lds)
    __builtin_amdgcn_global_load_lds((const AS1 unsigned int*)g,
                                     (AS3 unsigned int*)l, 16, 0, 0);
#else
    *(uint4*)l = *(const uint4*)g;
#endif
}

__device__ __forceinline__ unsigned short f2bf_rne(float x) {
    unsigned u = __float_as_uint(x);
    u += 0x7fffu + ((u >> 16) & 1u);
    return (unsigned short)(u >> 16);
}
__device__ __forceinline__ float bf2f(unsigned short b) {
    return __uint_as_float(((unsigned)b) << 16);
}

// RNE hi/lo split of an f32 pair into two packed-bf16 words using the
// packed convert (v_cvt_pk_bf16_f32). lo = x - hi is exact.
__device__ __forceinline__ void split2(float f0, float f1,
                                       unsigned& hp, unsigned& lp) {
    float2 v; v.x = f0; v.y = f1;
    __hip_bfloat162 h = __float22bfloat162_rn(v);
    unsigned hu; __builtin_memcpy(&hu, &h, 4);
    const float h0 = __uint_as_float(hu << 16);
    const float h1 = __uint_as_float(hu & 0xffff0000u);
    float2 l; l.x = f0 - h0; l.y = f1 - h1;
    __hip_bfloat162 lo = __float22bfloat162_rn(l);
    unsigned lu; __builtin_memcpy(&lu, &lo, 4);
    hp = hu; lp = lu;
}

// Swizzled flat position of element (n,k) in a prepped [N][256] bf16 array.
// Within each 32-k tile the 4 octets (8 els) are XOR-permuted by ((n>>1)&3)
// -> fragment reads spread across all 32 banks (0 conflicts, measured r3).
__device__ __forceinline__ int swz_pos(int n, int k) {
    const int base = k & ~31;
    const int o = (k >> 3) & 3;
    const int op = o ^ ((n >> 1) & 3);
    return n * 256 + base + (op << 3) + (k & 7);
}

// ---------------------------------------------------------------------------
// Prep: transpose + hi/lo-split (RNE) all three weight matrices into
// n-major swizzled bf16; concat biases for the fused off/attn projection.
// ---------------------------------------------------------------------------
__global__ __launch_bounds__(256) void prep_weights(
    const float* __restrict__ W_val, const float* __restrict__ W_off,
    const float* __restrict__ W_attn, const float* __restrict__ W_out,
    const float* __restrict__ b_off, const float* __restrict__ b_attn,
    unsigned short* __restrict__ Bval_h, unsigned short* __restrict__ Bval_l,
    unsigned short* __restrict__ Boa_h,  unsigned short* __restrict__ Boa_l,
    unsigned short* __restrict__ Bout_h, unsigned short* __restrict__ Bout_l,
    float* __restrict__ b_oa)
{
    const int t = blockIdx.x * 256 + threadIdx.x;
    if (t < 65536) {
        const int n = t >> 8, k = t & 255;
        const float x = W_val[k * 256 + n];
        const unsigned short hi = f2bf_rne(x);
        const unsigned short lo = f2bf_rne(x - bf2f(hi));
        const int p = swz_pos(n, k);
        Bval_h[p] = hi; Bval_l[p] = lo;
    } else if (t < 65536 + 98304) {
        const int t2 = t - 65536;
        const int n = t2 >> 8, k = t2 & 255;
        const float x = (n < 256) ? W_off[k * 256 + n] : W_attn[k * 128 + (n - 256)];
        const unsigned short hi = f2bf_rne(x);
        const unsigned short lo = f2bf_rne(x - bf2f(hi));
        const int p = swz_pos(n, k);
        Boa_h[p] = hi; Boa_l[p] = lo;
    } else if (t < 229376) {
        const int t3 = t - 163840;
        const int n = t3 >> 8, k = t3 & 255;
        const float x = W_out[k * 256 + n];
        const unsigned short hi = f2bf_rne(x);
        const unsigned short lo = f2bf_rne(x - bf2f(hi));
        const int p = swz_pos(n, k);
        Bout_h[p] = hi; Bout_l[p] = lo;
    } else {
        const int t4 = t - 229376;
        if (t4 < NOA) b_oa[t4] = (t4 < 256) ? b_off[t4] : b_attn[t4 - 256];
    }
}

// ---------------------------------------------------------------------------
// GEMM, f32 A: C = A(Mx256) @ B(256xN) + bias, bf16-split 3-product MFMA.
// r5 counted-vmcnt schedule + 2-DEEP A-register rotation:
//  * two A reg sets fr[0]/fr[1]; step t splits fr[t&1] (=A(t)) and refills
//    it with A(t+2). A(t) is force-completed at barrier-2(t-1) by the SAME
//    vmcnt(4) that forces B(t-1) (A(t) is older in the queue) after ~1.5
//    steps of cover -> HBM latency fully hidden; split(t) never waits.
//  * VMEM issue order per step: B(t) asyncs (4) then A(t+2) (4); enforced
//    by fence + sched_barrier so the vmcnt counts are exact.
//  * barrier-1: lgkmcnt(0) only. barrier-2: vmcnt(4) lgkmcnt(0) for t<6
//    (leaves only A(t+2) in flight), vmcnt(0) for t>=6 (tail drain).
// Hazard ledger: LDS WAR via barrier-1 lgkm; LDS publish via barrier-2
// (vmcnt forces B(t) asyncs, lgkm forces A ds_writes); A-reg WAR is
// in-thread (split before refill).
// LDS 32 KB single-buffered; octet-XOR swizzle (0 conflicts, measured).
// mode 0: Cf row-major [M][ldc] f32.
// mode 1: Cb = bf16 val layout C[((b*NH+h)*V_TOT+v)*HD+dh], row=(b,v), col=(h,dh)
// ---------------------------------------------------------------------------
__global__ __launch_bounds__(256, 3) void gemm_a32(
    const float* __restrict__ A,
    const unsigned short* __restrict__ Bh,
    const unsigned short* __restrict__ Bl,
    const float* __restrict__ bias,
    float* __restrict__ Cf,
    unsigned short* __restrict__ Cb,
    int ldc, int mode)
{
    __shared__ unsigned short Ah[128][32];        // octet-XOR swizzled
    __shared__ unsigned short Al[128][32];
    __shared__ unsigned short Bs[2][128][32];     // [hi/lo], swizzled octets

    const int tid  = threadIdx.x;
    const int col0 = blockIdx.x * 128;            // N-tile (fast axis)
    const int row0 = blockIdx.y * 128;            // M-tile
    const int wave = tid >> 6;
    const int lane = tid & 63;
    const int wm   = (wave >> 1) * 64;
    const int wn   = (wave & 1) * 64;
    const int m16  = lane & 15;
    const int quad = lane >> 4;

    // ---- per-thread A-staging coords (2 quarter-rows of 8 f32) ----
    const int i0  = tid;
    const int i1  = tid + 256;
    const int r0_ = i0 >> 2, o0_ = i0 & 3;
    const int r1_ = i1 >> 2, o1_ = i1 & 3;
    const int oo0 = (o0_ ^ ((r0_ >> 1) & 3)) << 3;   // swizzled LDS elem offset
    const int oo1 = (o1_ ^ ((r1_ >> 1) & 3)) << 3;
    const float* Ap0 = A + (size_t)(row0 + r0_) * 256 + o0_ * 8;
    const float* Ap1 = A + (size_t)(row0 + r1_) * 256 + o1_ * 8;

    // ---- per-thread B-staging pointers (hoisted; step advance = 64 B imm) ----
    const int lin0 = (wave * 2 + 0) * 1024 + lane * 16;
    const int lin1 = (wave * 2 + 1) * 1024 + lane * 16;
    const char* pBh0 = (const char*)Bh + ((size_t)(col0 + (lin0 >> 6)) * 256) * 2 + (lin0 & 63);
    const char* pBl0 = (const char*)Bl + ((size_t)(col0 + (lin0 >> 6)) * 256) * 2 + (lin0 & 63);
    const char* pBh1 = (const char*)Bh + ((size_t)(col0 + (lin1 >> 6)) * 256) * 2 + (lin1 & 63);
    const char* pBl1 = (const char*)Bl + ((size_t)(col0 + (lin1 >> 6)) * 256) * 2 + (lin1 & 63);
    char* lBh0 = (char*)&Bs[0][0][0] + lin0;
    char* lBh1 = (char*)&Bs[0][0][0] + lin1;
    char* lBl0 = (char*)&Bs[1][0][0] + lin0;
    char* lBl1 = (char*)&Bs[1][0][0] + lin1;

    v4f acc[4][4] = {};

    // ---- prologue: A(0) -> fr[0], A(1) -> fr[1] (2-deep rotation) ----
    float4 fr[2][4];
    fr[0][0] = *(const float4*)(Ap0);
    fr[0][1] = *(const float4*)(Ap0 + 4);
    fr[0][2] = *(const float4*)(Ap1);
    fr[0][3] = *(const float4*)(Ap1 + 4);
    fr[1][0] = *(const float4*)(Ap0 + 32);
    fr[1][1] = *(const float4*)(Ap0 + 36);
    fr[1][2] = *(const float4*)(Ap1 + 32);
    fr[1][3] = *(const float4*)(Ap1 + 36);

#pragma unroll
    for (int t = 0; t < 8; ++t) {
        const int ph = t & 1;                     // compile-time (full unroll)

        // ---- barrier-1 (raw): previous step's LDS readers done ----
        asm volatile("s_waitcnt lgkmcnt(0)" ::: "memory");
        __builtin_amdgcn_s_barrier();

        // ---- B(t) async global->LDS: oldest VMEM of this step ----
        copy16_async(pBh0 + t * 64, lBh0);
        copy16_async(pBh1 + t * 64, lBh1);
        copy16_async(pBl0 + t * 64, lBl0);
        copy16_async(pBl1 + t * 64, lBl1);

        // keep all later VMEM younger than the B asyncs (vmcnt counting)
        asm volatile("" ::: "memory");
        __builtin_amdgcn_sched_barrier(0);

        // ---- split A(t) = fr[ph] (already forced complete at barrier-2
        //      of step t-1 -> no wait here) ----
        unsigned hpk0[4], lpk0[4], hpk1[4], lpk1[4];
        split2(fr[ph][0].x, fr[ph][0].y, hpk0[0], lpk0[0]);
        split2(fr[ph][0].z, fr[ph][0].w, hpk0[1], lpk0[1]);
        split2(fr[ph][1].x, fr[ph][1].y, hpk0[2], lpk0[2]);
        split2(fr[ph][1].z, fr[ph][1].w, hpk0[3], lpk0[3]);
        split2(fr[ph][2].x, fr[ph][2].y, hpk1[0], lpk1[0]);
        split2(fr[ph][2].z, fr[ph][2].w, hpk1[1], lpk1[1]);
        split2(fr[ph][3].x, fr[ph][3].y, hpk1[2], lpk1[2]);
        split2(fr[ph][3].z, fr[ph][3].w, hpk1[3], lpk1[3]);

        // ---- refill fr[ph] with A(t+2) (youngest VMEM of this step) ----
        if (t < 6) {
            const int k2 = (t + 2) * 32;
            fr[ph][0] = *(const float4*)(Ap0 + k2);
            fr[ph][1] = *(const float4*)(Ap0 + k2 + 4);
            fr[ph][2] = *(const float4*)(Ap1 + k2);
            fr[ph][3] = *(const float4*)(Ap1 + k2 + 4);
        }

        // ---- A packed hi/lo -> LDS (b128, swizzled octet) ----
        *(uint4*)&Ah[r0_][oo0] = make_uint4(hpk0[0], hpk0[1], hpk0[2], hpk0[3]);
        *(uint4*)&Al[r0_][oo0] = make_uint4(lpk0[0], lpk0[1], lpk0[2], lpk0[3]);
        *(uint4*)&Ah[r1_][oo1] = make_uint4(hpk1[0], hpk1[1], hpk1[2], hpk1[3]);
        *(uint4*)&Al[r1_][oo1] = make_uint4(lpk1[0], lpk1[1], lpk1[2], lpk1[3]);

        // ---- barrier-2 (raw, counted): A ds_writes visible + B(t) landed
        //      + A(t+1) forced (older than B(t)); A(t+2) stays in flight ----
        if (t < 6) {
            asm volatile("s_waitcnt vmcnt(4) lgkmcnt(0)" ::: "memory");
        } else {
            asm volatile("s_waitcnt vmcnt(0) lgkmcnt(0)" ::: "memory");
        }
        __builtin_amdgcn_s_barrier();

        // ---- fragments (loop-invariant LDS addresses) + MFMA ----
#pragma unroll
        for (int i = 0; i < 4; ++i) {
            const int r  = wm + i * 16 + m16;
            const int ka = (quad ^ ((r >> 1) & 3)) << 3;
            const v8s ah = *(v8s*)&Ah[r][ka];
            const v8s al = *(v8s*)&Al[r][ka];
#pragma unroll
            for (int j = 0; j < 4; ++j) {
                const int n  = wn + j * 16 + m16;
                const int ko = (quad ^ ((n >> 1) & 3)) << 3;
                const v8s bh = *(v8s*)&Bs[0][n][ko];
                const v8s bl = *(v8s*)&Bs[1][n][ko];
                acc[i][j] = __builtin_amdgcn_mfma_f32_16x16x32_bf16(ah, bh, acc[i][j], 0, 0, 0);
                acc[i][j] = __builtin_amdgcn_mfma_f32_16x16x32_bf16(ah, bl, acc[i][j], 0, 0, 0);
                acc[i][j] = __builtin_amdgcn_mfma_f32_16x16x32_bf16(al, bh, acc[i][j], 0, 0, 0);
            }
        }
    }

    // ---- epilogue: D[row=quad*4+reg][col=lane&15] ----
#pragma unroll
    for (int j = 0; j < 4; ++j) {
        const int cl = col0 + wn + j * 16 + m16;
        const float bb = bias[cl];
        if (mode == 0) {
#pragma unroll
            for (int i = 0; i < 4; ++i)
#pragma unroll
                for (int r = 0; r < 4; ++r) {
                    const int R = row0 + wm + i * 16 + quad * 4 + r;
                    Cf[(size_t)R * ldc + cl] = acc[i][j][r] + bb;
                }
        } else {
            const int h  = cl >> 5;
            const int dh = cl & 31;
#pragma unroll
            for (int i = 0; i < 4; ++i)
#pragma unroll
                for (int r = 0; r < 4; ++r) {
                    const int R = row0 + wm + i * 16 + quad * 4 + r;
                    const unsigned b = (unsigned)R / V_TOT;
                    const int v = R - (int)b * V_TOT;
                    Cb[(((size_t)(b * NH + h)) * V_TOT + v) * HD + dh] =
                        f2bf_rne(acc[i][j][r] + bb);
                }
        }
    }
}

// ---------------------------------------------------------------------------
// GEMM, bf16 A (pre-swizzled rows): C = A(Mx256) @ B(256xN) + bias, f32 out.
// 2-product (A * (Bhi+Blo)). All operands async-staged, 2-phase pipelined,
// one barrier per K-step.
// ---------------------------------------------------------------------------
__global__ __launch_bounds__(256) void gemm_a16(
    const unsigned short* __restrict__ A,     // [M][256] bf16, swizzled octets
    const unsigned short* __restrict__ Bh,
    const unsigned short* __restrict__ Bl,
    const float* __restrict__ bias,
    float* __restrict__ C, int ldc)
{
    __shared__ unsigned short As[2][128][32];
    __shared__ unsigned short Bs[2][2][128][32];

    const int tid  = threadIdx.x;
    const int row0 = blockIdx.x * 128;
    const int col0 = blockIdx.y * 128;
    const int wave = tid >> 6;
    const int lane = tid & 63;
    const int wm   = (wave >> 1) * 64;
    const int wn   = (wave & 1) * 64;
    const int m16  = lane & 15;
    const int quad = lane >> 4;

    v4f acc[4][4] = {};

    // prologue: stage K-step 0 into buffer 0
#pragma unroll
    for (int c = 0; c < 2; ++c) {
        const int linear = (wave * 2 + c) * 1024 + lane * 16;
        const int n   = linear >> 6;
        const int off = linear & 63;
        copy16_async((const char*)A  + ((size_t)(row0 + n) * 256 + 0) * 2 + off,
                     (char*)&As[0][0][0] + linear);
        copy16_async((const char*)Bh + ((size_t)(col0 + n) * 256 + 0) * 2 + off,
                     (char*)&Bs[0][0][0][0] + linear);
        copy16_async((const char*)Bl + ((size_t)(col0 + n) * 256 + 0) * 2 + off,
                     (char*)&Bs[0][1][0][0] + linear);
    }
    __syncthreads();

    for (int t = 0; t < 8; ++t) {
        const int buf = t & 1;
        const int nb  = buf ^ 1;
        const int k1  = (t + 1) << 5;

        if (t < 7) {
#pragma unroll
            for (int c = 0; c < 2; ++c) {
                const int linear = (wave * 2 + c) * 1024 + lane * 16;
                const int n   = linear >> 6;
                const int off = linear & 63;
                copy16_async((const char*)A  + ((size_t)(row0 + n) * 256 + k1) * 2 + off,
                             (char*)&As[nb][0][0] + linear);
                copy16_async((const char*)Bh + ((size_t)(col0 + n) * 256 + k1) * 2 + off,
                             (char*)&Bs[nb][0][0][0] + linear);
                copy16_async((const char*)Bl + ((size_t)(col0 + n) * 256 + k1) * 2 + off,
                             (char*)&Bs[nb][1][0][0] + linear);
            }
        }

        v8s a[4], bh[4], bl[4];
#pragma unroll
        for (int i = 0; i < 4; ++i) {
            const int r  = wm + i * 16 + m16;
            const int ka = (quad ^ ((r >> 1) & 3)) << 3;
            a[i] = *(v8s*)&As[buf][r][ka];
            const int n  = wn + i * 16 + m16;
            const int kb = (quad ^ ((n >> 1) & 3)) << 3;
            bh[i] = *(v8s*)&Bs[buf][0][n][kb];
            bl[i] = *(v8s*)&Bs[buf][1][n][kb];
        }
#pragma unroll
        for (int i = 0; i < 4; ++i)
#pragma unroll
            for (int j = 0; j < 4; ++j) {
                acc[i][j] = __builtin_amdgcn_mfma_f32_16x16x32_bf16(a[i], bh[j], acc[i][j], 0, 0, 0);
                acc[i][j] = __builtin_amdgcn_mfma_f32_16x16x32_bf16(a[i], bl[j], acc[i][j], 0, 0, 0);
            }

        __syncthreads();
    }

#pragma unroll
    for (int j = 0; j < 4; ++j) {
        const int cl = col0 + wn + j * 16 + m16;
        const float bb = bias[cl];
#pragma unroll
        for (int i = 0; i < 4; ++i)
#pragma unroll
            for (int r = 0; r < 4; ++r) {
                const int R = row0 + wm + i * 16 + quad * 4 + r;
                C[(size_t)R * ldc + cl] = acc[i][j][r] + bb;
            }
    }
}

// ---------------------------------------------------------------------------
// Sampler: softmax(16) fused + bilinear gather from bf16 val + weighted sum.
// Thread = (bq, h, d8): d8 indexes an octet of 8 channels; 4 lanes with the
// same (bq,h) read one contiguous 64B line per corner. Output pre is bf16
// with the GEMM octet swizzle baked in (row n = bq).
// ---------------------------------------------------------------------------
__global__ __launch_bounds__(256) void sample_kernel(
    const float* __restrict__ refp,
    const float* __restrict__ offattn,            // [9600][384]
    const unsigned short* __restrict__ val,       // [b][h][V][32] bf16
    unsigned short* __restrict__ pre)             // [9600][256] bf16 swizzled
{
    const int t  = blockIdx.x * 256 + threadIdx.x;  // 0 .. 307199
    const int d8 = t & 3;
    const int h  = (t >> 2) & 7;
    const int bq = t >> 5;
    const int b  = bq / NQ;

    const float* rp = refp + (size_t)bq * 8;
    const float* op = offattn + (size_t)bq * 384 + h * 32;
    const float* ap = offattn + (size_t)bq * 384 + 256 + h * 16;

    // softmax over the 16 (l,p) logits
    float aw[16];
    float m = -1e30f;
#pragma unroll
    for (int i = 0; i < 16; ++i) { aw[i] = ap[i]; m = fmaxf(m, aw[i]); }
    float s = 0.f;
#pragma unroll
    for (int i = 0; i < 16; ++i) { aw[i] = __expf(aw[i] - m); s += aw[i]; }
    const float inv = 1.f / s;
#pragma unroll
    for (int i = 0; i < 16; ++i) aw[i] *= inv;

    const int Hs[4] = {80, 40, 20, 10};
    const int St[4] = {0, 6400, 8000, 8400};

    float acc[8] = {};
#pragma unroll
    for (int l = 0; l < NL; ++l) {
        const int Wl = Hs[l], Hl = Hs[l];
        const float fW = (float)Wl, fH = (float)Hl;
        const float rx = rp[l * 2 + 0];
        const float ry = rp[l * 2 + 1];
        const unsigned short* vb =
            val + (((size_t)(b * NH + h)) * V_TOT + St[l]) * HD + d8 * 8;
#pragma unroll
        for (int p = 0; p < NP; ++p) {
            const float ox = op[l * 8 + p * 2 + 0];
            const float oy = op[l * 8 + p * 2 + 1];
            const float w  = aw[l * 4 + p];
            const float x = fmaf(rx, fW, ox) - 0.5f;
            const float y = fmaf(ry, fH, oy) - 0.5f;
            const float x0f = floorf(x), y0f = floorf(y);
            const int   x0 = (int)x0f,  y0 = (int)y0f;
            const float wx1 = x - x0f,  wy1 = y - y0f;
            const float wx0 = 1.f - wx1, wy0 = 1.f - wy1;
#pragma unroll
            for (int cy = 0; cy < 2; ++cy) {
#pragma unroll
                for (int cx = 0; cx < 2; ++cx) {
                    const int xi = x0 + cx;
                    const int yi = y0 + cy;
                    float cw = (cx ? wx1 : wx0) * (cy ? wy1 : wy0) * w;
                    const bool valid = (xi >= 0) && (xi < Wl) && (yi >= 0) && (yi < Hl);
                    cw = valid ? cw : 0.f;
                    const int xc = xi < 0 ? 0 : (xi > Wl - 1 ? Wl - 1 : xi);
                    const int yc = yi < 0 ? 0 : (yi > Hl - 1 ? Hl - 1 : yi);
                    const uint4 g = *(const uint4*)(vb + (size_t)(yc * Wl + xc) * HD);
                    const unsigned gu[4] = {g.x, g.y, g.z, g.w};
#pragma unroll
                    for (int e = 0; e < 4; ++e) {
                        acc[2*e]   = fmaf(cw, __uint_as_float(gu[e] << 16),        acc[2*e]);
                        acc[2*e+1] = fmaf(cw, __uint_as_float(gu[e] & 0xffff0000u), acc[2*e+1]);
                    }
                }
            }
        }
    }

    // pack to bf16 and store with the A-octet swizzle for gemm_a16
    unsigned o[4];
#pragma unroll
    for (int e = 0; e < 4; ++e)
        o[e] = (unsigned)f2bf_rne(acc[2*e]) | ((unsigned)f2bf_rne(acc[2*e+1]) << 16);
    const int octswz = d8 ^ ((bq >> 1) & 3);
    *(uint4*)(pre + (size_t)bq * 256 + h * 32 + octswz * 8) =
        make_uint4(o[0], o[1], o[2], o[3]);
}

// ---------------------------------------------------------------------------
extern "C" void kernel_launch(void* const* d_in, const int* in_sizes, int n_in,
                              void* d_out, int out_size, void* d_ws, size_t ws_size,
                              hipStream_t stream)
{
    const float* query  = (const float*)d_in[0];
    const float* refp   = (const float*)d_in[1];
    const float* value  = (const float*)d_in[2];
    const float* W_off  = (const float*)d_in[5];
    const float* b_off  = (const float*)d_in[6];
    const float* W_attn = (const float*)d_in[7];
    const float* b_attn = (const float*)d_in[8];
    const float* W_val  = (const float*)d_in[9];
    const float* b_val  = (const float*)d_in[10];
    const float* W_out  = (const float*)d_in[11];
    const float* b_out  = (const float*)d_in[12];
    float* out = (float*)d_out;

    char* ws = (char*)d_ws;
    unsigned short* val     = (unsigned short*)ws;                       // 139,264,000 B
    float*          offattn = (float*)(ws + 139264000);                  // 14,745,600 B
    unsigned short* pre     = (unsigned short*)(ws + 154009600);         //  4,915,200 B
    unsigned short* Bval_h  = (unsigned short*)(ws + 158924800);         //    131,072 B
    unsigned short* Bval_l  = Bval_h + 65536;
    unsigned short* Boa_h   = Bval_l + 65536;                            //    196,608 B
    unsigned short* Boa_l   = Boa_h + 98304;
    unsigned short* Bout_h  = Boa_l + 98304;
    unsigned short* Bout_l  = Bout_h + 65536;
    float*          b_oa    = (float*)(Bout_l + 65536);

    const dim3 blk(256);

    // 0) weight prep: transpose + RNE hi/lo split + swizzle + bias concat
    prep_weights<<<dim3(898), blk, 0, stream>>>(
        W_val, W_off, W_attn, W_out, b_off, b_attn,
        Bval_h, Bval_l, Boa_h, Boa_l, Bout_h, Bout_l, b_oa);

    // 1) val = value @ W_val + b_val -> bf16 [b][h][V][hd]   (grid: x=Ntile)
    gemm_a32<<<dim3(2, MVAL / 128), blk, 0, stream>>>(
        value, Bval_h, Bval_l, b_val, nullptr, val, 0, 1);

    // 2) fused off+attn projection -> f32 [9600][384]
    gemm_a32<<<dim3(3, BQ_TOT / 128), blk, 0, stream>>>(
        query, Boa_h, Boa_l, b_oa, offattn, nullptr, NOA, 0);

    // 3) softmax + bilinear sampling + weighted sum -> pre bf16 (swizzled)
    sample_kernel<<<dim3((BQ_TOT * 32) / 256), blk, 0, stream>>>(
        refp, offattn, val, pre);

    // 4) out = pre @ W_out + b_out -> f32 [9600][256]
    gemm_a16<<<dim3(BQ_TOT / 128, 2), blk, 0, stream>>>(
        pre, Bout_h, Bout_l, b_out, out, 256);
}

// Round 7
// 913.386 us; speedup vs baseline: 1.0231x; 1.0231x over previous
//
#include <hip/hip_runtime.h>
#include <hip/hip_bf16.h>
#include <math.h>
#include <stdint.h>

// Problem constants (deterministic from setup_inputs)
#define NB 32
#define NQ 300
#define ND 256
#define NH 8
#define HD 32
#define NL 4
#define NP 4
#define V_TOT 8500           // 6400+1600+400+100
#define BQ_TOT (NB*NQ)       // 9600
#define MVAL (NB*V_TOT)      // 272000
#define NOA 384              // fused off(256)+attn(128) cols

typedef short v8s __attribute__((ext_vector_type(8)));
typedef float v4f __attribute__((ext_vector_type(4)));

#define AS1 __attribute__((address_space(1)))
#define AS3 __attribute__((address_space(3)))

__device__ __forceinline__ void copy16_async(const void* g, void* l) {
#if __has_builtin(__builtin_amdgcn_global_load_lds)
    __builtin_amdgcn_global_load_lds((const AS1 unsigned int*)g,
                                     (AS3 unsigned int*)l, 16, 0, 0);
#else
    *(uint4*)l = *(const uint4*)g;
#endif
}

__device__ __forceinline__ unsigned short f2bf_rne(float x) {
    unsigned u = __float_as_uint(x);
    u += 0x7fffu + ((u >> 16) & 1u);
    return (unsigned short)(u >> 16);
}
__device__ __forceinline__ float bf2f(unsigned short b) {
    return __uint_as_float(((unsigned)b) << 16);
}

// RNE hi/lo split of an f32 pair into two packed-bf16 words using the
// packed convert (v_cvt_pk_bf16_f32). lo = x - hi is exact.
__device__ __forceinline__ void split2(float f0, float f1,
                                       unsigned& hp, unsigned& lp) {
    float2 v; v.x = f0; v.y = f1;
    __hip_bfloat162 h = __float22bfloat162_rn(v);
    unsigned hu; __builtin_memcpy(&hu, &h, 4);
    const float h0 = __uint_as_float(hu << 16);
    const float h1 = __uint_as_float(hu & 0xffff0000u);
    float2 l; l.x = f0 - h0; l.y = f1 - h1;
    __hip_bfloat162 lo = __float22bfloat162_rn(l);
    unsigned lu; __builtin_memcpy(&lu, &lo, 4);
    hp = hu; lp = lu;
}

// Swizzled flat position of element (n,k) in a prepped [N][256] bf16 array.
// Within each 32-k tile the 4 octets (8 els) are XOR-permuted by ((n>>1)&3)
// -> fragment reads spread across all 32 banks (0 conflicts, measured r3).
__device__ __forceinline__ int swz_pos(int n, int k) {
    const int base = k & ~31;
    const int o = (k >> 3) & 3;
    const int op = o ^ ((n >> 1) & 3);
    return n * 256 + base + (op << 3) + (k & 7);
}

// ---------------------------------------------------------------------------
// Prep: transpose + hi/lo-split (RNE) all three weight matrices into
// n-major swizzled bf16; concat biases for the fused off/attn projection.
// ---------------------------------------------------------------------------
__global__ __launch_bounds__(256) void prep_weights(
    const float* __restrict__ W_val, const float* __restrict__ W_off,
    const float* __restrict__ W_attn, const float* __restrict__ W_out,
    const float* __restrict__ b_off, const float* __restrict__ b_attn,
    unsigned short* __restrict__ Bval_h, unsigned short* __restrict__ Bval_l,
    unsigned short* __restrict__ Boa_h,  unsigned short* __restrict__ Boa_l,
    unsigned short* __restrict__ Bout_h, unsigned short* __restrict__ Bout_l,
    float* __restrict__ b_oa)
{
    const int t = blockIdx.x * 256 + threadIdx.x;
    if (t < 65536) {
        const int n = t >> 8, k = t & 255;
        const float x = W_val[k * 256 + n];
        const unsigned short hi = f2bf_rne(x);
        const unsigned short lo = f2bf_rne(x - bf2f(hi));
        const int p = swz_pos(n, k);
        Bval_h[p] = hi; Bval_l[p] = lo;
    } else if (t < 65536 + 98304) {
        const int t2 = t - 65536;
        const int n = t2 >> 8, k = t2 & 255;
        const float x = (n < 256) ? W_off[k * 256 + n] : W_attn[k * 128 + (n - 256)];
        const unsigned short hi = f2bf_rne(x);
        const unsigned short lo = f2bf_rne(x - bf2f(hi));
        const int p = swz_pos(n, k);
        Boa_h[p] = hi; Boa_l[p] = lo;
    } else if (t < 229376) {
        const int t3 = t - 163840;
        const int n = t3 >> 8, k = t3 & 255;
        const float x = W_out[k * 256 + n];
        const unsigned short hi = f2bf_rne(x);
        const unsigned short lo = f2bf_rne(x - bf2f(hi));
        const int p = swz_pos(n, k);
        Bout_h[p] = hi; Bout_l[p] = lo;
    } else {
        const int t4 = t - 229376;
        if (t4 < NOA) b_oa[t4] = (t4 < 256) ? b_off[t4] : b_attn[t4 - 256];
    }
}

// ---------------------------------------------------------------------------
// GEMM, f32 A: C = A(Mx256) @ B(256xN) + bias, bf16-split 3-product MFMA.
// r6 counted-vmcnt schedule + 2-deep A rotation, re-expressed with NAMED
// register sets (rule #20: SROA runs before unroll; any variable-indexed
// local array goes to scratch -> r6's 1.5 GB of spill traffic). The 8
// K-steps are emitted explicitly via a macro whose A-set argument is
// textual, so every access is compile-time and stays in VGPRs.
// Schedule per step t (set S = A(t) regs):
//   barrier-1: lgkmcnt(0) only.
//   B(t) asyncs (oldest VMEM) | fence+sched_barrier | split S |
//   refill S with A(t+2) (youngest) | A ds_writes |
//   barrier-2: vmcnt(4) lgkmcnt(0) for t<6 (queue = [A(t+1)x4, B(t)x4,
//   A(t+2)x4]; forces A(t+1)+B(t), leaves A(t+2) flying), vmcnt(0) t>=6.
// Hazard ledger: LDS WAR via barrier-1 lgkm; LDS publish via barrier-2
// (vmcnt forces B(t), lgkm forces A ds_writes); A-reg WAR in-thread.
// LDS 32 KB single-buffered; octet-XOR swizzle (0 conflicts, measured).
// mode 0: Cf row-major [M][ldc] f32.
// mode 1: Cb = bf16 val layout C[((b*NH+h)*V_TOT+v)*HD+dh], row=(b,v), col=(h,dh)
// ---------------------------------------------------------------------------
__global__ __launch_bounds__(256, 3) void gemm_a32(
    const float* __restrict__ A,
    const unsigned short* __restrict__ Bh,
    const unsigned short* __restrict__ Bl,
    const float* __restrict__ bias,
    float* __restrict__ Cf,
    unsigned short* __restrict__ Cb,
    int ldc, int mode)
{
    __shared__ unsigned short Ah[128][32];        // octet-XOR swizzled
    __shared__ unsigned short Al[128][32];
    __shared__ unsigned short Bs[2][128][32];     // [hi/lo], swizzled octets

    const int tid  = threadIdx.x;
    const int col0 = blockIdx.x * 128;            // N-tile (fast axis)
    const int row0 = blockIdx.y * 128;            // M-tile
    const int wave = tid >> 6;
    const int lane = tid & 63;
    const int wm   = (wave >> 1) * 64;
    const int wn   = (wave & 1) * 64;
    const int m16  = lane & 15;
    const int quad = lane >> 4;

    // ---- per-thread A-staging coords (2 quarter-rows of 8 f32) ----
    const int i0  = tid;
    const int i1  = tid + 256;
    const int r0_ = i0 >> 2, o0_ = i0 & 3;
    const int r1_ = i1 >> 2, o1_ = i1 & 3;
    const int oo0 = (o0_ ^ ((r0_ >> 1) & 3)) << 3;   // swizzled LDS elem offset
    const int oo1 = (o1_ ^ ((r1_ >> 1) & 3)) << 3;
    const float* Ap0 = A + (size_t)(row0 + r0_) * 256 + o0_ * 8;
    const float* Ap1 = A + (size_t)(row0 + r1_) * 256 + o1_ * 8;

    // ---- per-thread B-staging pointers (hoisted; step advance = 64 B imm) ----
    const int lin0 = (wave * 2 + 0) * 1024 + lane * 16;
    const int lin1 = (wave * 2 + 1) * 1024 + lane * 16;
    const char* pBh0 = (const char*)Bh + ((size_t)(col0 + (lin0 >> 6)) * 256) * 2 + (lin0 & 63);
    const char* pBl0 = (const char*)Bl + ((size_t)(col0 + (lin0 >> 6)) * 256) * 2 + (lin0 & 63);
    const char* pBh1 = (const char*)Bh + ((size_t)(col0 + (lin1 >> 6)) * 256) * 2 + (lin1 & 63);
    const char* pBl1 = (const char*)Bl + ((size_t)(col0 + (lin1 >> 6)) * 256) * 2 + (lin1 & 63);
    char* lBh0 = (char*)&Bs[0][0][0] + lin0;
    char* lBh1 = (char*)&Bs[0][0][0] + lin1;
    char* lBl0 = (char*)&Bs[1][0][0] + lin0;
    char* lBl1 = (char*)&Bs[1][0][0] + lin1;

    v4f acc[4][4] = {};

    // ---- prologue: A(0) -> set a, A(1) -> set b (named, never arrays) ----
    float4 a0 = *(const float4*)(Ap0);
    float4 a1 = *(const float4*)(Ap0 + 4);
    float4 a2 = *(const float4*)(Ap1);
    float4 a3 = *(const float4*)(Ap1 + 4);
    float4 b0 = *(const float4*)(Ap0 + 32);
    float4 b1 = *(const float4*)(Ap0 + 36);
    float4 b2 = *(const float4*)(Ap1 + 32);
    float4 b3 = *(const float4*)(Ap1 + 36);

#define GSTEP(T, F0, F1, F2, F3)                                              \
    {                                                                         \
        asm volatile("s_waitcnt lgkmcnt(0)" ::: "memory");                    \
        __builtin_amdgcn_s_barrier();                                         \
        copy16_async(pBh0 + (T) * 64, lBh0);                                  \
        copy16_async(pBh1 + (T) * 64, lBh1);                                  \
        copy16_async(pBl0 + (T) * 64, lBl0);                                  \
        copy16_async(pBl1 + (T) * 64, lBl1);                                  \
        asm volatile("" ::: "memory");                                        \
        __builtin_amdgcn_sched_barrier(0);                                    \
        unsigned hq0, lq0, hq1, lq1, hq2, lq2, hq3, lq3;                      \
        unsigned hr0, lr0, hr1, lr1, hr2, lr2, hr3, lr3;                      \
        split2(F0.x, F0.y, hq0, lq0);                                         \
        split2(F0.z, F0.w, hq1, lq1);                                         \
        split2(F1.x, F1.y, hq2, lq2);                                         \
        split2(F1.z, F1.w, hq3, lq3);                                         \
        split2(F2.x, F2.y, hr0, lr0);                                         \
        split2(F2.z, F2.w, hr1, lr1);                                         \
        split2(F3.x, F3.y, hr2, lr2);                                         \
        split2(F3.z, F3.w, hr3, lr3);                                         \
        if ((T) < 6) {                                                        \
            F0 = *(const float4*)(Ap0 + ((T) + 2) * 32);                      \
            F1 = *(const float4*)(Ap0 + ((T) + 2) * 32 + 4);                  \
            F2 = *(const float4*)(Ap1 + ((T) + 2) * 32);                      \
            F3 = *(const float4*)(Ap1 + ((T) + 2) * 32 + 4);                  \
        }                                                                     \
        *(uint4*)&Ah[r0_][oo0] = make_uint4(hq0, hq1, hq2, hq3);              \
        *(uint4*)&Al[r0_][oo0] = make_uint4(lq0, lq1, lq2, lq3);              \
        *(uint4*)&Ah[r1_][oo1] = make_uint4(hr0, hr1, hr2, hr3);              \
        *(uint4*)&Al[r1_][oo1] = make_uint4(lr0, lr1, lr2, lr3);              \
        if ((T) < 6) {                                                        \
            asm volatile("s_waitcnt vmcnt(4) lgkmcnt(0)" ::: "memory");       \
        } else {                                                              \
            asm volatile("s_waitcnt vmcnt(0) lgkmcnt(0)" ::: "memory");       \
        }                                                                     \
        __builtin_amdgcn_s_barrier();                                         \
        _Pragma("unroll")                                                     \
        for (int i = 0; i < 4; ++i) {                                         \
            const int r  = wm + i * 16 + m16;                                 \
            const int ka = (quad ^ ((r >> 1) & 3)) << 3;                      \
            const v8s ah = *(v8s*)&Ah[r][ka];                                 \
            const v8s al = *(v8s*)&Al[r][ka];                                 \
            _Pragma("unroll")                                                 \
            for (int j = 0; j < 4; ++j) {                                     \
                const int n  = wn + j * 16 + m16;                             \
                const int ko = (quad ^ ((n >> 1) & 3)) << 3;                  \
                const v8s bh = *(v8s*)&Bs[0][n][ko];                          \
                const v8s bl = *(v8s*)&Bs[1][n][ko];                          \
                acc[i][j] = __builtin_amdgcn_mfma_f32_16x16x32_bf16(ah, bh, acc[i][j], 0, 0, 0); \
                acc[i][j] = __builtin_amdgcn_mfma_f32_16x16x32_bf16(ah, bl, acc[i][j], 0, 0, 0); \
                acc[i][j] = __builtin_amdgcn_mfma_f32_16x16x32_bf16(al, bh, acc[i][j], 0, 0, 0); \
            }                                                                 \
        }                                                                     \
    }

    GSTEP(0, a0, a1, a2, a3)
    GSTEP(1, b0, b1, b2, b3)
    GSTEP(2, a0, a1, a2, a3)
    GSTEP(3, b0, b1, b2, b3)
    GSTEP(4, a0, a1, a2, a3)
    GSTEP(5, b0, b1, b2, b3)
    GSTEP(6, a0, a1, a2, a3)
    GSTEP(7, b0, b1, b2, b3)
#undef GSTEP

    // ---- epilogue: D[row=quad*4+reg][col=lane&15] ----
#pragma unroll
    for (int j = 0; j < 4; ++j) {
        const int cl = col0 + wn + j * 16 + m16;
        const float bb = bias[cl];
        if (mode == 0) {
#pragma unroll
            for (int i = 0; i < 4; ++i)
#pragma unroll
                for (int r = 0; r < 4; ++r) {
                    const int R = row0 + wm + i * 16 + quad * 4 + r;
                    Cf[(size_t)R * ldc + cl] = acc[i][j][r] + bb;
                }
        } else {
            const int h  = cl >> 5;
            const int dh = cl & 31;
#pragma unroll
            for (int i = 0; i < 4; ++i)
#pragma unroll
                for (int r = 0; r < 4; ++r) {
                    const int R = row0 + wm + i * 16 + quad * 4 + r;
                    const unsigned b = (unsigned)R / V_TOT;
                    const int v = R - (int)b * V_TOT;
                    Cb[(((size_t)(b * NH + h)) * V_TOT + v) * HD + dh] =
                        f2bf_rne(acc[i][j][r] + bb);
                }
        }
    }
}

// ---------------------------------------------------------------------------
// GEMM, bf16 A (pre-swizzled rows): C = A(Mx256) @ B(256xN) + bias, f32 out.
// 2-product (A * (Bhi+Blo)). All operands async-staged, 2-phase pipelined,
// one barrier per K-step.
// ---------------------------------------------------------------------------
__global__ __launch_bounds__(256) void gemm_a16(
    const unsigned short* __restrict__ A,     // [M][256] bf16, swizzled octets
    const unsigned short* __restrict__ Bh,
    const unsigned short* __restrict__ Bl,
    const float* __restrict__ bias,
    float* __restrict__ C, int ldc)
{
    __shared__ unsigned short As[2][128][32];
    __shared__ unsigned short Bs[2][2][128][32];

    const int tid  = threadIdx.x;
    const int row0 = blockIdx.x * 128;
    const int col0 = blockIdx.y * 128;
    const int wave = tid >> 6;
    const int lane = tid & 63;
    const int wm   = (wave >> 1) * 64;
    const int wn   = (wave & 1) * 64;
    const int m16  = lane & 15;
    const int quad = lane >> 4;

    v4f acc[4][4] = {};

    // prologue: stage K-step 0 into buffer 0
#pragma unroll
    for (int c = 0; c < 2; ++c) {
        const int linear = (wave * 2 + c) * 1024 + lane * 16;
        const int n   = linear >> 6;
        const int off = linear & 63;
        copy16_async((const char*)A  + ((size_t)(row0 + n) * 256 + 0) * 2 + off,
                     (char*)&As[0][0][0] + linear);
        copy16_async((const char*)Bh + ((size_t)(col0 + n) * 256 + 0) * 2 + off,
                     (char*)&Bs[0][0][0][0] + linear);
        copy16_async((const char*)Bl + ((size_t)(col0 + n) * 256 + 0) * 2 + off,
                     (char*)&Bs[0][1][0][0] + linear);
    }
    __syncthreads();

    for (int t = 0; t < 8; ++t) {
        const int buf = t & 1;
        const int nb  = buf ^ 1;
        const int k1  = (t + 1) << 5;

        if (t < 7) {
#pragma unroll
            for (int c = 0; c < 2; ++c) {
                const int linear = (wave * 2 + c) * 1024 + lane * 16;
                const int n   = linear >> 6;
                const int off = linear & 63;
                copy16_async((const char*)A  + ((size_t)(row0 + n) * 256 + k1) * 2 + off,
                             (char*)&As[nb][0][0] + linear);
                copy16_async((const char*)Bh + ((size_t)(col0 + n) * 256 + k1) * 2 + off,
                             (char*)&Bs[nb][0][0][0] + linear);
                copy16_async((const char*)Bl + ((size_t)(col0 + n) * 256 + k1) * 2 + off,
                             (char*)&Bs[nb][1][0][0] + linear);
            }
        }

        v8s a[4], bh[4], bl[4];
#pragma unroll
        for (int i = 0; i < 4; ++i) {
            const int r  = wm + i * 16 + m16;
            const int ka = (quad ^ ((r >> 1) & 3)) << 3;
            a[i] = *(v8s*)&As[buf][r][ka];
            const int n  = wn + i * 16 + m16;
            const int kb = (quad ^ ((n >> 1) & 3)) << 3;
            bh[i] = *(v8s*)&Bs[buf][0][n][kb];
            bl[i] = *(v8s*)&Bs[buf][1][n][kb];
        }
#pragma unroll
        for (int i = 0; i < 4; ++i)
#pragma unroll
            for (int j = 0; j < 4; ++j) {
                acc[i][j] = __builtin_amdgcn_mfma_f32_16x16x32_bf16(a[i], bh[j], acc[i][j], 0, 0, 0);
                acc[i][j] = __builtin_amdgcn_mfma_f32_16x16x32_bf16(a[i], bl[j], acc[i][j], 0, 0, 0);
            }

        __syncthreads();
    }

#pragma unroll
    for (int j = 0; j < 4; ++j) {
        const int cl = col0 + wn + j * 16 + m16;
        const float bb = bias[cl];
#pragma unroll
        for (int i = 0; i < 4; ++i)
#pragma unroll
            for (int r = 0; r < 4; ++r) {
                const int R = row0 + wm + i * 16 + quad * 4 + r;
                C[(size_t)R * ldc + cl] = acc[i][j][r] + bb;
            }
    }
}

// ---------------------------------------------------------------------------
// Sampler: softmax(16) fused + bilinear gather from bf16 val + weighted sum.
// Thread = (bq, h, d8): d8 indexes an octet of 8 channels; 4 lanes with the
// same (bq,h) read one contiguous 64B line per corner. Output pre is bf16
// with the GEMM octet swizzle baked in (row n = bq).
// ---------------------------------------------------------------------------
__global__ __launch_bounds__(256) void sample_kernel(
    const float* __restrict__ refp,
    const float* __restrict__ offattn,            // [9600][384]
    const unsigned short* __restrict__ val,       // [b][h][V][32] bf16
    unsigned short* __restrict__ pre)             // [9600][256] bf16 swizzled
{
    const int t  = blockIdx.x * 256 + threadIdx.x;  // 0 .. 307199
    const int d8 = t & 3;
    const int h  = (t >> 2) & 7;
    const int bq = t >> 5;
    const int b  = bq / NQ;

    const float* rp = refp + (size_t)bq * 8;
    const float* op = offattn + (size_t)bq * 384 + h * 32;
    const float* ap = offattn + (size_t)bq * 384 + 256 + h * 16;

    // softmax over the 16 (l,p) logits
    float aw[16];
    float m = -1e30f;
#pragma unroll
    for (int i = 0; i < 16; ++i) { aw[i] = ap[i]; m = fmaxf(m, aw[i]); }
    float s = 0.f;
#pragma unroll
    for (int i = 0; i < 16; ++i) { aw[i] = __expf(aw[i] - m); s += aw[i]; }
    const float inv = 1.f / s;
#pragma unroll
    for (int i = 0; i < 16; ++i) aw[i] *= inv;

    const int Hs[4] = {80, 40, 20, 10};
    const int St[4] = {0, 6400, 8000, 8400};

    float acc[8] = {};
#pragma unroll
    for (int l = 0; l < NL; ++l) {
        const int Wl = Hs[l], Hl = Hs[l];
        const float fW = (float)Wl, fH = (float)Hl;
        const float rx = rp[l * 2 + 0];
        const float ry = rp[l * 2 + 1];
        const unsigned short* vb =
            val + (((size_t)(b * NH + h)) * V_TOT + St[l]) * HD + d8 * 8;
#pragma unroll
        for (int p = 0; p < NP; ++p) {
            const float ox = op[l * 8 + p * 2 + 0];
            const float oy = op[l * 8 + p * 2 + 1];
            const float w  = aw[l * 4 + p];
            const float x = fmaf(rx, fW, ox) - 0.5f;
            const float y = fmaf(ry, fH, oy) - 0.5f;
            const float x0f = floorf(x), y0f = floorf(y);
            const int   x0 = (int)x0f,  y0 = (int)y0f;
            const float wx1 = x - x0f,  wy1 = y - y0f;
            const float wx0 = 1.f - wx1, wy0 = 1.f - wy1;
#pragma unroll
            for (int cy = 0; cy < 2; ++cy) {
#pragma unroll
                for (int cx = 0; cx < 2; ++cx) {
                    const int xi = x0 + cx;
                    const int yi = y0 + cy;
                    float cw = (cx ? wx1 : wx0) * (cy ? wy1 : wy0) * w;
                    const bool valid = (xi >= 0) && (xi < Wl) && (yi >= 0) && (yi < Hl);
                    cw = valid ? cw : 0.f;
                    const int xc = xi < 0 ? 0 : (xi > Wl - 1 ? Wl - 1 : xi);
                    const int yc = yi < 0 ? 0 : (yi > Hl - 1 ? Hl - 1 : yi);
                    const uint4 g = *(const uint4*)(vb + (size_t)(yc * Wl + xc) * HD);
                    const unsigned gu[4] = {g.x, g.y, g.z, g.w};
#pragma unroll
                    for (int e = 0; e < 4; ++e) {
                        acc[2*e]   = fmaf(cw, __uint_as_float(gu[e] << 16),        acc[2*e]);
                        acc[2*e+1] = fmaf(cw, __uint_as_float(gu[e] & 0xffff0000u), acc[2*e+1]);
                    }
                }
            }
        }
    }

    // pack to bf16 and store with the A-octet swizzle for gemm_a16
    unsigned o[4];
#pragma unroll
    for (int e = 0; e < 4; ++e)
        o[e] = (unsigned)f2bf_rne(acc[2*e]) | ((unsigned)f2bf_rne(acc[2*e+1]) << 16);
    const int octswz = d8 ^ ((bq >> 1) & 3);
    *(uint4*)(pre + (size_t)bq * 256 + h * 32 + octswz * 8) =
        make_uint4(o[0], o[1], o[2], o[3]);
}

// ---------------------------------------------------------------------------
extern "C" void kernel_launch(void* const* d_in, const int* in_sizes, int n_in,
                              void* d_out, int out_size, void* d_ws, size_t ws_size,
                              hipStream_t stream)
{
    const float* query  = (const float*)d_in[0];
    const float* refp   = (const float*)d_in[1];
    const float* value  = (const float*)d_in[2];
    const float* W_off  = (const float*)d_in[5];
    const float* b_off  = (const float*)d_in[6];
    const float* W_attn = (const float*)d_in[7];
    const float* b_attn = (const float*)d_in[8];
    const float* W_val  = (const float*)d_in[9];
    const float* b_val  = (const float*)d_in[10];
    const float* W_out  = (const float*)d_in[11];
    const float* b_out  = (const float*)d_in[12];
    float* out = (float*)d_out;

    char* ws = (char*)d_ws;
    unsigned short* val     = (unsigned short*)ws;                       // 139,264,000 B
    float*          offattn = (float*)(ws + 139264000);                  // 14,745,600 B
    unsigned short* pre     = (unsigned short*)(ws + 154009600);         //  4,915,200 B
    unsigned short* Bval_h  = (unsigned short*)(ws + 158924800);         //    131,072 B
    unsigned short* Bval_l  = Bval_h + 65536;
    unsigned short* Boa_h   = Bval_l + 65536;                            //    196,608 B
    unsigned short* Boa_l   = Boa_h + 98304;
    unsigned short* Bout_h  = Boa_l + 98304;
    unsigned short* Bout_l  = Bout_h + 65536;
    float*          b_oa    = (float*)(Bout_l + 65536);

    const dim3 blk(256);

    // 0) weight prep: transpose + RNE hi/lo split + swizzle + bias concat
    prep_weights<<<dim3(898), blk, 0, stream>>>(
        W_val, W_off, W_attn, W_out, b_off, b_attn,
        Bval_h, Bval_l, Boa_h, Boa_l, Bout_h, Bout_l, b_oa);

    // 1) val = value @ W_val + b_val -> bf16 [b][h][V][hd]   (grid: x=Ntile)
    gemm_a32<<<dim3(2, MVAL / 128), blk, 0, stream>>>(
        value, Bval_h, Bval_l, b_val, nullptr, val, 0, 1);

    // 2) fused off+attn projection -> f32 [9600][384]
    gemm_a32<<<dim3(3, BQ_TOT / 128), blk, 0, stream>>>(
        query, Boa_h, Boa_l, b_oa, offattn, nullptr, NOA, 0);

    // 3) softmax + bilinear sampling + weighted sum -> pre bf16 (swizzled)
    sample_kernel<<<dim3((BQ_TOT * 32) / 256), blk, 0, stream>>>(
        refp, offattn, val, pre);

    // 4) out = pre @ W_out + b_out -> f32 [9600][256]
    gemm_a16<<<dim3(BQ_TOT / 128, 2), blk, 0, stream>>>(
        pre, Bout_h, Bout_l, b_out, out, 256);
}

// Round 8
// 588.510 us; speedup vs baseline: 1.5878x; 1.5520x over previous
//
#include <hip/hip_runtime.h>
#include <hip/hip_bf16.h>
#include <math.h>
#include <stdint.h>

// Problem constants (deterministic from setup_inputs)
#define NB 32
#define NQ 300
#define ND 256
#define NH 8
#define HD 32
#define NL 4
#define NP 4
#define V_TOT 8500           // 6400+1600+400+100
#define BQ_TOT (NB*NQ)       // 9600
#define MVAL (NB*V_TOT)      // 272000
#define NOA 384              // fused off(256)+attn(128) cols

typedef short v8s __attribute__((ext_vector_type(8)));
typedef float v4f __attribute__((ext_vector_type(4)));

#define AS1 __attribute__((address_space(1)))
#define AS3 __attribute__((address_space(3)))

__device__ __forceinline__ void copy16_async(const void* g, void* l) {
#if __has_builtin(__builtin_amdgcn_global_load_lds)
    __builtin_amdgcn_global_load_lds((const AS1 unsigned int*)g,
                                     (AS3 unsigned int*)l, 16, 0, 0);
#else
    *(uint4*)l = *(const uint4*)g;
#endif
}

__device__ __forceinline__ unsigned short f2bf_rne(float x) {
    unsigned u = __float_as_uint(x);
    u += 0x7fffu + ((u >> 16) & 1u);
    return (unsigned short)(u >> 16);
}
__device__ __forceinline__ float bf2f(unsigned short b) {
    return __uint_as_float(((unsigned)b) << 16);
}

// RNE hi/lo split of an f32 pair into two packed-bf16 words using the
// packed convert (v_cvt_pk_bf16_f32). lo = x - hi is exact.
__device__ __forceinline__ void split2(float f0, float f1,
                                       unsigned& hp, unsigned& lp) {
    float2 v; v.x = f0; v.y = f1;
    __hip_bfloat162 h = __float22bfloat162_rn(v);
    unsigned hu; __builtin_memcpy(&hu, &h, 4);
    const float h0 = __uint_as_float(hu << 16);
    const float h1 = __uint_as_float(hu & 0xffff0000u);
    float2 l; l.x = f0 - h0; l.y = f1 - h1;
    __hip_bfloat162 lo = __float22bfloat162_rn(l);
    unsigned lu; __builtin_memcpy(&lu, &lo, 4);
    hp = hu; lp = lu;
}

// Swizzled flat position of element (n,k) in a prepped [N][256] bf16 array.
// Within each 32-k tile the 4 octets (8 els) are XOR-permuted by ((n>>1)&3)
// -> fragment reads spread across all 32 banks (0 conflicts, measured r3).
__device__ __forceinline__ int swz_pos(int n, int k) {
    const int base = k & ~31;
    const int o = (k >> 3) & 3;
    const int op = o ^ ((n >> 1) & 3);
    return n * 256 + base + (op << 3) + (k & 7);
}

// ---------------------------------------------------------------------------
// Prep: transpose + hi/lo-split (RNE) all three weight matrices into
// n-major swizzled bf16; concat biases for the fused off/attn projection.
// ---------------------------------------------------------------------------
__global__ __launch_bounds__(256) void prep_weights(
    const float* __restrict__ W_val, const float* __restrict__ W_off,
    const float* __restrict__ W_attn, const float* __restrict__ W_out,
    const float* __restrict__ b_off, const float* __restrict__ b_attn,
    unsigned short* __restrict__ Bval_h, unsigned short* __restrict__ Bval_l,
    unsigned short* __restrict__ Boa_h,  unsigned short* __restrict__ Boa_l,
    unsigned short* __restrict__ Bout_h, unsigned short* __restrict__ Bout_l,
    float* __restrict__ b_oa)
{
    const int t = blockIdx.x * 256 + threadIdx.x;
    if (t < 65536) {
        const int n = t >> 8, k = t & 255;
        const float x = W_val[k * 256 + n];
        const unsigned short hi = f2bf_rne(x);
        const unsigned short lo = f2bf_rne(x - bf2f(hi));
        const int p = swz_pos(n, k);
        Bval_h[p] = hi; Bval_l[p] = lo;
    } else if (t < 65536 + 98304) {
        const int t2 = t - 65536;
        const int n = t2 >> 8, k = t2 & 255;
        const float x = (n < 256) ? W_off[k * 256 + n] : W_attn[k * 128 + (n - 256)];
        const unsigned short hi = f2bf_rne(x);
        const unsigned short lo = f2bf_rne(x - bf2f(hi));
        const int p = swz_pos(n, k);
        Boa_h[p] = hi; Boa_l[p] = lo;
    } else if (t < 229376) {
        const int t3 = t - 163840;
        const int n = t3 >> 8, k = t3 & 255;
        const float x = W_out[k * 256 + n];
        const unsigned short hi = f2bf_rne(x);
        const unsigned short lo = f2bf_rne(x - bf2f(hi));
        const int p = swz_pos(n, k);
        Bout_h[p] = hi; Bout_l[p] = lo;
    } else {
        const int t4 = t - 229376;
        if (t4 < NOA) b_oa[t4] = (t4 < 256) ? b_off[t4] : b_attn[t4 - 256];
    }
}

// ---------------------------------------------------------------------------
// GEMM, f32 A: C = A(Mx256) @ B(256xN) + bias, bf16-split 3-product MFMA.
// r7 counted-vmcnt schedule + 2-deep A rotation (named register sets),
// with __launch_bounds__(256, 2): the (256,3) bound capped the unified
// file at ~168/wave (split ~84 VGPR + 84 AGPR) and the allocator SPILLED
// the second rotation set to scratch (r6/r7: +1.5 GB HBM traffic, VGPR
// pinned at 84). Budget 256/wave lets both A-sets live in VGPRs; at ~150
// total regs HW occupancy still lands at 3 waves/SIMD naturally.
// Schedule per step t (set S = A(t) regs):
//   barrier-1: lgkmcnt(0) only.
//   B(t) asyncs (oldest VMEM) | fence+sched_barrier | split S |
//   refill S with A(t+2) (youngest) | A ds_writes |
//   barrier-2: vmcnt(4) lgkmcnt(0) for t<6 (queue = [A(t+1)x4, B(t)x4,
//   A(t+2)x4]; forces A(t+1)+B(t), leaves A(t+2) flying), vmcnt(0) t>=6.
// Hazard ledger: LDS WAR via barrier-1 lgkm; LDS publish via barrier-2
// (vmcnt forces B(t), lgkm forces A ds_writes); A-reg WAR in-thread.
// LDS 32 KB single-buffered; octet-XOR swizzle (0 conflicts, measured).
// mode 0: Cf row-major [M][ldc] f32.
// mode 1: Cb = bf16 val layout C[((b*NH+h)*V_TOT+v)*HD+dh], row=(b,v), col=(h,dh)
// ---------------------------------------------------------------------------
__global__ __launch_bounds__(256, 2) void gemm_a32(
    const float* __restrict__ A,
    const unsigned short* __restrict__ Bh,
    const unsigned short* __restrict__ Bl,
    const float* __restrict__ bias,
    float* __restrict__ Cf,
    unsigned short* __restrict__ Cb,
    int ldc, int mode)
{
    __shared__ unsigned short Ah[128][32];        // octet-XOR swizzled
    __shared__ unsigned short Al[128][32];
    __shared__ unsigned short Bs[2][128][32];     // [hi/lo], swizzled octets

    const int tid  = threadIdx.x;
    const int col0 = blockIdx.x * 128;            // N-tile (fast axis)
    const int row0 = blockIdx.y * 128;            // M-tile
    const int wave = tid >> 6;
    const int lane = tid & 63;
    const int wm   = (wave >> 1) * 64;
    const int wn   = (wave & 1) * 64;
    const int m16  = lane & 15;
    const int quad = lane >> 4;

    // ---- per-thread A-staging coords (2 quarter-rows of 8 f32) ----
    const int i0  = tid;
    const int i1  = tid + 256;
    const int r0_ = i0 >> 2, o0_ = i0 & 3;
    const int r1_ = i1 >> 2, o1_ = i1 & 3;
    const int oo0 = (o0_ ^ ((r0_ >> 1) & 3)) << 3;   // swizzled LDS elem offset
    const int oo1 = (o1_ ^ ((r1_ >> 1) & 3)) << 3;
    const float* Ap0 = A + (size_t)(row0 + r0_) * 256 + o0_ * 8;
    const float* Ap1 = A + (size_t)(row0 + r1_) * 256 + o1_ * 8;

    // ---- per-thread B-staging pointers (hoisted; step advance = 64 B imm) ----
    const int lin0 = (wave * 2 + 0) * 1024 + lane * 16;
    const int lin1 = (wave * 2 + 1) * 1024 + lane * 16;
    const char* pBh0 = (const char*)Bh + ((size_t)(col0 + (lin0 >> 6)) * 256) * 2 + (lin0 & 63);
    const char* pBl0 = (const char*)Bl + ((size_t)(col0 + (lin0 >> 6)) * 256) * 2 + (lin0 & 63);
    const char* pBh1 = (const char*)Bh + ((size_t)(col0 + (lin1 >> 6)) * 256) * 2 + (lin1 & 63);
    const char* pBl1 = (const char*)Bl + ((size_t)(col0 + (lin1 >> 6)) * 256) * 2 + (lin1 & 63);
    char* lBh0 = (char*)&Bs[0][0][0] + lin0;
    char* lBh1 = (char*)&Bs[0][0][0] + lin1;
    char* lBl0 = (char*)&Bs[1][0][0] + lin0;
    char* lBl1 = (char*)&Bs[1][0][0] + lin1;

    v4f acc[4][4] = {};

    // ---- prologue: A(0) -> set a, A(1) -> set b (named, never arrays) ----
    float4 a0 = *(const float4*)(Ap0);
    float4 a1 = *(const float4*)(Ap0 + 4);
    float4 a2 = *(const float4*)(Ap1);
    float4 a3 = *(const float4*)(Ap1 + 4);
    float4 b0 = *(const float4*)(Ap0 + 32);
    float4 b1 = *(const float4*)(Ap0 + 36);
    float4 b2 = *(const float4*)(Ap1 + 32);
    float4 b3 = *(const float4*)(Ap1 + 36);

#define GSTEP(T, F0, F1, F2, F3)                                              \
    {                                                                         \
        asm volatile("s_waitcnt lgkmcnt(0)" ::: "memory");                    \
        __builtin_amdgcn_s_barrier();                                         \
        copy16_async(pBh0 + (T) * 64, lBh0);                                  \
        copy16_async(pBh1 + (T) * 64, lBh1);                                  \
        copy16_async(pBl0 + (T) * 64, lBl0);                                  \
        copy16_async(pBl1 + (T) * 64, lBl1);                                  \
        asm volatile("" ::: "memory");                                        \
        __builtin_amdgcn_sched_barrier(0);                                    \
        unsigned hq0, lq0, hq1, lq1, hq2, lq2, hq3, lq3;                      \
        unsigned hr0, lr0, hr1, lr1, hr2, lr2, hr3, lr3;                      \
        split2(F0.x, F0.y, hq0, lq0);                                         \
        split2(F0.z, F0.w, hq1, lq1);                                         \
        split2(F1.x, F1.y, hq2, lq2);                                         \
        split2(F1.z, F1.w, hq3, lq3);                                         \
        split2(F2.x, F2.y, hr0, lr0);                                         \
        split2(F2.z, F2.w, hr1, lr1);                                         \
        split2(F3.x, F3.y, hr2, lr2);                                         \
        split2(F3.z, F3.w, hr3, lr3);                                         \
        if ((T) < 6) {                                                        \
            F0 = *(const float4*)(Ap0 + ((T) + 2) * 32);                      \
            F1 = *(const float4*)(Ap0 + ((T) + 2) * 32 + 4);                  \
            F2 = *(const float4*)(Ap1 + ((T) + 2) * 32);                      \
            F3 = *(const float4*)(Ap1 + ((T) + 2) * 32 + 4);                  \
        }                                                                     \
        *(uint4*)&Ah[r0_][oo0] = make_uint4(hq0, hq1, hq2, hq3);              \
        *(uint4*)&Al[r0_][oo0] = make_uint4(lq0, lq1, lq2, lq3);              \
        *(uint4*)&Ah[r1_][oo1] = make_uint4(hr0, hr1, hr2, hr3);              \
        *(uint4*)&Al[r1_][oo1] = make_uint4(lr0, lr1, lr2, lr3);              \
        if ((T) < 6) {                                                        \
            asm volatile("s_waitcnt vmcnt(4) lgkmcnt(0)" ::: "memory");       \
        } else {                                                              \
            asm volatile("s_waitcnt vmcnt(0) lgkmcnt(0)" ::: "memory");       \
        }                                                                     \
        __builtin_amdgcn_s_barrier();                                         \
        _Pragma("unroll")                                                     \
        for (int i = 0; i < 4; ++i) {                                         \
            const int r  = wm + i * 16 + m16;                                 \
            const int ka = (quad ^ ((r >> 1) & 3)) << 3;                      \
            const v8s ah = *(v8s*)&Ah[r][ka];                                 \
            const v8s al = *(v8s*)&Al[r][ka];                                 \
            _Pragma("unroll")                                                 \
            for (int j = 0; j < 4; ++j) {                                     \
                const int n  = wn + j * 16 + m16;                             \
                const int ko = (quad ^ ((n >> 1) & 3)) << 3;                  \
                const v8s bh = *(v8s*)&Bs[0][n][ko];                          \
                const v8s bl = *(v8s*)&Bs[1][n][ko];                          \
                acc[i][j] = __builtin_amdgcn_mfma_f32_16x16x32_bf16(ah, bh, acc[i][j], 0, 0, 0); \
                acc[i][j] = __builtin_amdgcn_mfma_f32_16x16x32_bf16(ah, bl, acc[i][j], 0, 0, 0); \
                acc[i][j] = __builtin_amdgcn_mfma_f32_16x16x32_bf16(al, bh, acc[i][j], 0, 0, 0); \
            }                                                                 \
        }                                                                     \
    }

    GSTEP(0, a0, a1, a2, a3)
    GSTEP(1, b0, b1, b2, b3)
    GSTEP(2, a0, a1, a2, a3)
    GSTEP(3, b0, b1, b2, b3)
    GSTEP(4, a0, a1, a2, a3)
    GSTEP(5, b0, b1, b2, b3)
    GSTEP(6, a0, a1, a2, a3)
    GSTEP(7, b0, b1, b2, b3)
#undef GSTEP

    // ---- epilogue: D[row=quad*4+reg][col=lane&15] ----
#pragma unroll
    for (int j = 0; j < 4; ++j) {
        const int cl = col0 + wn + j * 16 + m16;
        const float bb = bias[cl];
        if (mode == 0) {
#pragma unroll
            for (int i = 0; i < 4; ++i)
#pragma unroll
                for (int r = 0; r < 4; ++r) {
                    const int R = row0 + wm + i * 16 + quad * 4 + r;
                    Cf[(size_t)R * ldc + cl] = acc[i][j][r] + bb;
                }
        } else {
            const int h  = cl >> 5;
            const int dh = cl & 31;
#pragma unroll
            for (int i = 0; i < 4; ++i)
#pragma unroll
                for (int r = 0; r < 4; ++r) {
                    const int R = row0 + wm + i * 16 + quad * 4 + r;
                    const unsigned b = (unsigned)R / V_TOT;
                    const int v = R - (int)b * V_TOT;
                    Cb[(((size_t)(b * NH + h)) * V_TOT + v) * HD + dh] =
                        f2bf_rne(acc[i][j][r] + bb);
                }
        }
    }
}

// ---------------------------------------------------------------------------
// GEMM, bf16 A (pre-swizzled rows): C = A(Mx256) @ B(256xN) + bias, f32 out.
// 2-product (A * (Bhi+Blo)). All operands async-staged, 2-phase pipelined,
// one barrier per K-step.
// ---------------------------------------------------------------------------
__global__ __launch_bounds__(256) void gemm_a16(
    const unsigned short* __restrict__ A,     // [M][256] bf16, swizzled octets
    const unsigned short* __restrict__ Bh,
    const unsigned short* __restrict__ Bl,
    const float* __restrict__ bias,
    float* __restrict__ C, int ldc)
{
    __shared__ unsigned short As[2][128][32];
    __shared__ unsigned short Bs[2][2][128][32];

    const int tid  = threadIdx.x;
    const int row0 = blockIdx.x * 128;
    const int col0 = blockIdx.y * 128;
    const int wave = tid >> 6;
    const int lane = tid & 63;
    const int wm   = (wave >> 1) * 64;
    const int wn   = (wave & 1) * 64;
    const int m16  = lane & 15;
    const int quad = lane >> 4;

    v4f acc[4][4] = {};

    // prologue: stage K-step 0 into buffer 0
#pragma unroll
    for (int c = 0; c < 2; ++c) {
        const int linear = (wave * 2 + c) * 1024 + lane * 16;
        const int n   = linear >> 6;
        const int off = linear & 63;
        copy16_async((const char*)A  + ((size_t)(row0 + n) * 256 + 0) * 2 + off,
                     (char*)&As[0][0][0] + linear);
        copy16_async((const char*)Bh + ((size_t)(col0 + n) * 256 + 0) * 2 + off,
                     (char*)&Bs[0][0][0][0] + linear);
        copy16_async((const char*)Bl + ((size_t)(col0 + n) * 256 + 0) * 2 + off,
                     (char*)&Bs[0][1][0][0] + linear);
    }
    __syncthreads();

    for (int t = 0; t < 8; ++t) {
        const int buf = t & 1;
        const int nb  = buf ^ 1;
        const int k1  = (t + 1) << 5;

        if (t < 7) {
#pragma unroll
            for (int c = 0; c < 2; ++c) {
                const int linear = (wave * 2 + c) * 1024 + lane * 16;
                const int n   = linear >> 6;
                const int off = linear & 63;
                copy16_async((const char*)A  + ((size_t)(row0 + n) * 256 + k1) * 2 + off,
                             (char*)&As[nb][0][0] + linear);
                copy16_async((const char*)Bh + ((size_t)(col0 + n) * 256 + k1) * 2 + off,
                             (char*)&Bs[nb][0][0][0] + linear);
                copy16_async((const char*)Bl + ((size_t)(col0 + n) * 256 + k1) * 2 + off,
                             (char*)&Bs[nb][1][0][0] + linear);
            }
        }

        v8s a[4], bh[4], bl[4];
#pragma unroll
        for (int i = 0; i < 4; ++i) {
            const int r  = wm + i * 16 + m16;
            const int ka = (quad ^ ((r >> 1) & 3)) << 3;
            a[i] = *(v8s*)&As[buf][r][ka];
            const int n  = wn + i * 16 + m16;
            const int kb = (quad ^ ((n >> 1) & 3)) << 3;
            bh[i] = *(v8s*)&Bs[buf][0][n][kb];
            bl[i] = *(v8s*)&Bs[buf][1][n][kb];
        }
#pragma unroll
        for (int i = 0; i < 4; ++i)
#pragma unroll
            for (int j = 0; j < 4; ++j) {
                acc[i][j] = __builtin_amdgcn_mfma_f32_16x16x32_bf16(a[i], bh[j], acc[i][j], 0, 0, 0);
                acc[i][j] = __builtin_amdgcn_mfma_f32_16x16x32_bf16(a[i], bl[j], acc[i][j], 0, 0, 0);
            }

        __syncthreads();
    }

#pragma unroll
    for (int j = 0; j < 4; ++j) {
        const int cl = col0 + wn + j * 16 + m16;
        const float bb = bias[cl];
#pragma unroll
        for (int i = 0; i < 4; ++i)
#pragma unroll
            for (int r = 0; r < 4; ++r) {
                const int R = row0 + wm + i * 16 + quad * 4 + r;
                C[(size_t)R * ldc + cl] = acc[i][j][r] + bb;
            }
    }
}

// ---------------------------------------------------------------------------
// Sampler: softmax(16) fused + bilinear gather from bf16 val + weighted sum.
// Thread = (bq, h, d8): d8 indexes an octet of 8 channels; 4 lanes with the
// same (bq,h) read one contiguous 64B line per corner. Output pre is bf16
// with the GEMM octet swizzle baked in (row n = bq).
// ---------------------------------------------------------------------------
__global__ __launch_bounds__(256) void sample_kernel(
    const float* __restrict__ refp,
    const float* __restrict__ offattn,            // [9600][384]
    const unsigned short* __restrict__ val,       // [b][h][V][32] bf16
    unsigned short* __restrict__ pre)             // [9600][256] bf16 swizzled
{
    const int t  = blockIdx.x * 256 + threadIdx.x;  // 0 .. 307199
    const int d8 = t & 3;
    const int h  = (t >> 2) & 7;
    const int bq = t >> 5;
    const int b  = bq / NQ;

    const float* rp = refp + (size_t)bq * 8;
    const float* op = offattn + (size_t)bq * 384 + h * 32;
    const float* ap = offattn + (size_t)bq * 384 + 256 + h * 16;

    // softmax over the 16 (l,p) logits
    float aw[16];
    float m = -1e30f;
#pragma unroll
    for (int i = 0; i < 16; ++i) { aw[i] = ap[i]; m = fmaxf(m, aw[i]); }
    float s = 0.f;
#pragma unroll
    for (int i = 0; i < 16; ++i) { aw[i] = __expf(aw[i] - m); s += aw[i]; }
    const float inv = 1.f / s;
#pragma unroll
    for (int i = 0; i < 16; ++i) aw[i] *= inv;

    const int Hs[4] = {80, 40, 20, 10};
    const int St[4] = {0, 6400, 8000, 8400};

    float acc[8] = {};
#pragma unroll
    for (int l = 0; l < NL; ++l) {
        const int Wl = Hs[l], Hl = Hs[l];
        const float fW = (float)Wl, fH = (float)Hl;
        const float rx = rp[l * 2 + 0];
        const float ry = rp[l * 2 + 1];
        const unsigned short* vb =
            val + (((size_t)(b * NH + h)) * V_TOT + St[l]) * HD + d8 * 8;
#pragma unroll
        for (int p = 0; p < NP; ++p) {
            const float ox = op[l * 8 + p * 2 + 0];
            const float oy = op[l * 8 + p * 2 + 1];
            const float w  = aw[l * 4 + p];
            const float x = fmaf(rx, fW, ox) - 0.5f;
            const float y = fmaf(ry, fH, oy) - 0.5f;
            const float x0f = floorf(x), y0f = floorf(y);
            const int   x0 = (int)x0f,  y0 = (int)y0f;
            const float wx1 = x - x0f,  wy1 = y - y0f;
            const float wx0 = 1.f - wx1, wy0 = 1.f - wy1;
#pragma unroll
            for (int cy = 0; cy < 2; ++cy) {
#pragma unroll
                for (int cx = 0; cx < 2; ++cx) {
                    const int xi = x0 + cx;
                    const int yi = y0 + cy;
                    float cw = (cx ? wx1 : wx0) * (cy ? wy1 : wy0) * w;
                    const bool valid = (xi >= 0) && (xi < Wl) && (yi >= 0) && (yi < Hl);
                    cw = valid ? cw : 0.f;
                    const int xc = xi < 0 ? 0 : (xi > Wl - 1 ? Wl - 1 : xi);
                    const int yc = yi < 0 ? 0 : (yi > Hl - 1 ? Hl - 1 : yi);
                    const uint4 g = *(const uint4*)(vb + (size_t)(yc * Wl + xc) * HD);
                    const unsigned gu[4] = {g.x, g.y, g.z, g.w};
#pragma unroll
                    for (int e = 0; e < 4; ++e) {
                        acc[2*e]   = fmaf(cw, __uint_as_float(gu[e] << 16),        acc[2*e]);
                        acc[2*e+1] = fmaf(cw, __uint_as_float(gu[e] & 0xffff0000u), acc[2*e+1]);
                    }
                }
            }
        }
    }

    // pack to bf16 and store with the A-octet swizzle for gemm_a16
    unsigned o[4];
#pragma unroll
    for (int e = 0; e < 4; ++e)
        o[e] = (unsigned)f2bf_rne(acc[2*e]) | ((unsigned)f2bf_rne(acc[2*e+1]) << 16);
    const int octswz = d8 ^ ((bq >> 1) & 3);
    *(uint4*)(pre + (size_t)bq * 256 + h * 32 + octswz * 8) =
        make_uint4(o[0], o[1], o[2], o[3]);
}

// ---------------------------------------------------------------------------
extern "C" void kernel_launch(void* const* d_in, const int* in_sizes, int n_in,
                              void* d_out, int out_size, void* d_ws, size_t ws_size,
                              hipStream_t stream)
{
    const float* query  = (const float*)d_in[0];
    const float* refp   = (const float*)d_in[1];
    const float* value  = (const float*)d_in[2];
    const float* W_off  = (const float*)d_in[5];
    const float* b_off  = (const float*)d_in[6];
    const float* W_attn = (const float*)d_in[7];
    const float* b_attn = (const float*)d_in[8];
    const float* W_val  = (const float*)d_in[9];
    const float* b_val  = (const float*)d_in[10];
    const float* W_out  = (const float*)d_in[11];
    const float* b_out  = (const float*)d_in[12];
    float* out = (float*)d_out;

    char* ws = (char*)d_ws;
    unsigned short* val     = (unsigned short*)ws;                       // 139,264,000 B
    float*          offattn = (float*)(ws + 139264000);                  // 14,745,600 B
    unsigned short* pre     = (unsigned short*)(ws + 154009600);         //  4,915,200 B
    unsigned short* Bval_h  = (unsigned short*)(ws + 158924800);         //    131,072 B
    unsigned short* Bval_l  = Bval_h + 65536;
    unsigned short* Boa_h   = Bval_l + 65536;                            //    196,608 B
    unsigned short* Boa_l   = Boa_h + 98304;
    unsigned short* Bout_h  = Boa_l + 98304;
    unsigned short* Bout_l  = Bout_h + 65536;
    float*          b_oa    = (float*)(Bout_l + 65536);

    const dim3 blk(256);

    // 0) weight prep: transpose + RNE hi/lo split + swizzle + bias concat
    prep_weights<<<dim3(898), blk, 0, stream>>>(
        W_val, W_off, W_attn, W_out, b_off, b_attn,
        Bval_h, Bval_l, Boa_h, Boa_l, Bout_h, Bout_l, b_oa);

    // 1) val = value @ W_val + b_val -> bf16 [b][h][V][hd]   (grid: x=Ntile)
    gemm_a32<<<dim3(2, MVAL / 128), blk, 0, stream>>>(
        value, Bval_h, Bval_l, b_val, nullptr, val, 0, 1);

    // 2) fused off+attn projection -> f32 [9600][384]
    gemm_a32<<<dim3(3, BQ_TOT / 128), blk, 0, stream>>>(
        query, Boa_h, Boa_l, b_oa, offattn, nullptr, NOA, 0);

    // 3) softmax + bilinear sampling + weighted sum -> pre bf16 (swizzled)
    sample_kernel<<<dim3((BQ_TOT * 32) / 256), blk, 0, stream>>>(
        refp, offattn, val, pre);

    // 4) out = pre @ W_out + b_out -> f32 [9600][256]
    gemm_a16<<<dim3(BQ_TOT / 128, 2), blk, 0, stream>>>(
        pre, Bout_h, Bout_l, b_out, out, 256);
}

// Round 9
// 531.321 us; speedup vs baseline: 1.7587x; 1.1076x over previous
//
#include <hip/hip_runtime.h>
#include <hip/hip_bf16.h>
#include <math.h>
#include <stdint.h>

// Problem constants (deterministic from setup_inputs)
#define NB 32
#define NQ 300
#define ND 256
#define NH 8
#define HD 32
#define NL 4
#define NP 4
#define V_TOT 8500           // 6400+1600+400+100
#define BQ_TOT (NB*NQ)       // 9600
#define MVAL (NB*V_TOT)      // 272000
#define NOA 384              // fused off(256)+attn(128) cols

typedef short v8s __attribute__((ext_vector_type(8)));
typedef float v4f __attribute__((ext_vector_type(4)));

#define AS1 __attribute__((address_space(1)))
#define AS3 __attribute__((address_space(3)))

__device__ __forceinline__ void copy16_async(const void* g, void* l) {
#if __has_builtin(__builtin_amdgcn_global_load_lds)
    __builtin_amdgcn_global_load_lds((const AS1 unsigned int*)g,
                                     (AS3 unsigned int*)l, 16, 0, 0);
#else
    *(uint4*)l = *(const uint4*)g;
#endif
}

__device__ __forceinline__ unsigned short f2bf_rne(float x) {
    unsigned u = __float_as_uint(x);
    u += 0x7fffu + ((u >> 16) & 1u);
    return (unsigned short)(u >> 16);
}
__device__ __forceinline__ float bf2f(unsigned short b) {
    return __uint_as_float(((unsigned)b) << 16);
}

// RNE hi/lo split of an f32 pair into two packed-bf16 words using the
// packed convert (v_cvt_pk_bf16_f32). lo = x - hi is exact.
__device__ __forceinline__ void split2(float f0, float f1,
                                       unsigned& hp, unsigned& lp) {
    float2 v; v.x = f0; v.y = f1;
    __hip_bfloat162 h = __float22bfloat162_rn(v);
    unsigned hu; __builtin_memcpy(&hu, &h, 4);
    const float h0 = __uint_as_float(hu << 16);
    const float h1 = __uint_as_float(hu & 0xffff0000u);
    float2 l; l.x = f0 - h0; l.y = f1 - h1;
    __hip_bfloat162 lo = __float22bfloat162_rn(l);
    unsigned lu; __builtin_memcpy(&lu, &lo, 4);
    hp = hu; lp = lu;
}

// Swizzled flat position of element (n,k) in a prepped [N][256] bf16 array.
// Within each 32-k tile the 4 octets (8 els) are XOR-permuted by ((n>>1)&3)
// -> fragment reads spread across all 32 banks (0 conflicts, measured r3).
__device__ __forceinline__ int swz_pos(int n, int k) {
    const int base = k & ~31;
    const int o = (k >> 3) & 3;
    const int op = o ^ ((n >> 1) & 3);
    return n * 256 + base + (op << 3) + (k & 7);
}

// ---------------------------------------------------------------------------
// Prep: transpose + hi/lo-split (RNE) all three weight matrices into
// n-major swizzled bf16; concat biases for the fused off/attn projection.
// ---------------------------------------------------------------------------
__global__ __launch_bounds__(256) void prep_weights(
    const float* __restrict__ W_val, const float* __restrict__ W_off,
    const float* __restrict__ W_attn, const float* __restrict__ W_out,
    const float* __restrict__ b_off, const float* __restrict__ b_attn,
    unsigned short* __restrict__ Bval_h, unsigned short* __restrict__ Bval_l,
    unsigned short* __restrict__ Boa_h,  unsigned short* __restrict__ Boa_l,
    unsigned short* __restrict__ Bout_h, unsigned short* __restrict__ Bout_l,
    float* __restrict__ b_oa)
{
    const int t = blockIdx.x * 256 + threadIdx.x;
    if (t < 65536) {
        const int n = t >> 8, k = t & 255;
        const float x = W_val[k * 256 + n];
        const unsigned short hi = f2bf_rne(x);
        const unsigned short lo = f2bf_rne(x - bf2f(hi));
        const int p = swz_pos(n, k);
        Bval_h[p] = hi; Bval_l[p] = lo;
    } else if (t < 65536 + 98304) {
        const int t2 = t - 65536;
        const int n = t2 >> 8, k = t2 & 255;
        const float x = (n < 256) ? W_off[k * 256 + n] : W_attn[k * 128 + (n - 256)];
        const unsigned short hi = f2bf_rne(x);
        const unsigned short lo = f2bf_rne(x - bf2f(hi));
        const int p = swz_pos(n, k);
        Boa_h[p] = hi; Boa_l[p] = lo;
    } else if (t < 229376) {
        const int t3 = t - 163840;
        const int n = t3 >> 8, k = t3 & 255;
        const float x = W_out[k * 256 + n];
        const unsigned short hi = f2bf_rne(x);
        const unsigned short lo = f2bf_rne(x - bf2f(hi));
        const int p = swz_pos(n, k);
        Bout_h[p] = hi; Bout_l[p] = lo;
    } else {
        const int t4 = t - 229376;
        if (t4 < NOA) b_oa[t4] = (t4 < 256) ? b_off[t4] : b_attn[t4 - 256];
    }
}

// ---------------------------------------------------------------------------
// GEMM, f32 A: C = A(Mx256) @ B(256xN) + bias, bf16-split 3-product MFMA.
// r5 schedule RESTORED VERBATIM (best measured: val ~163 us, VGPR 84,
// 3 blocks/CU). The 2-deep rotation arc (r6-r8) is closed: under (256,3)
// it spills (+1.5 GB scratch traffic); under (256,2) it fits (124 VGPR)
// but drops occupancy 31->21% and nets -15% vs this kernel.
//  * barrier-1: lgkmcnt(0) only (previous step's LDS readers done).
//  * B(t) asyncs issued FIRST (oldest VMEM), then split, then A(t+1)
//    prefetch (youngest), then A ds_writes.
//  * barrier-2: s_waitcnt vmcnt(4) lgkmcnt(0) -> forces exactly the B(t)
//    asyncs complete while the 4 A(t+1) global loads STAY IN FLIGHT
//    across the barrier + MFMA(t); consumed at split(t+1). vmcnt(0) at t=7.
// Hazard ledger: LDS WAR via barrier-1 lgkm; LDS publish via barrier-2
// (vmcnt forces B asyncs, lgkm forces A ds_writes); issue-order B<A via
// fence + sched_barrier. LDS 32 KB; octet-XOR swizzle (0 conflicts).
// mode 0: Cf row-major [M][ldc] f32.
// mode 1: Cb = bf16 val layout C[((b*NH+h)*V_TOT+v)*HD+dh], row=(b,v), col=(h,dh)
// ---------------------------------------------------------------------------
__global__ __launch_bounds__(256, 3) void gemm_a32(
    const float* __restrict__ A,
    const unsigned short* __restrict__ Bh,
    const unsigned short* __restrict__ Bl,
    const float* __restrict__ bias,
    float* __restrict__ Cf,
    unsigned short* __restrict__ Cb,
    int ldc, int mode)
{
    __shared__ unsigned short Ah[128][32];        // octet-XOR swizzled
    __shared__ unsigned short Al[128][32];
    __shared__ unsigned short Bs[2][128][32];     // [hi/lo], swizzled octets

    const int tid  = threadIdx.x;
    const int col0 = blockIdx.x * 128;            // N-tile (fast axis)
    const int row0 = blockIdx.y * 128;            // M-tile
    const int wave = tid >> 6;
    const int lane = tid & 63;
    const int wm   = (wave >> 1) * 64;
    const int wn   = (wave & 1) * 64;
    const int m16  = lane & 15;
    const int quad = lane >> 4;

    // ---- per-thread A-staging coords (2 quarter-rows of 8 f32) ----
    const int i0  = tid;
    const int i1  = tid + 256;
    const int r0_ = i0 >> 2, o0_ = i0 & 3;
    const int r1_ = i1 >> 2, o1_ = i1 & 3;
    const int oo0 = (o0_ ^ ((r0_ >> 1) & 3)) << 3;   // swizzled LDS elem offset
    const int oo1 = (o1_ ^ ((r1_ >> 1) & 3)) << 3;
    const float* Ap0 = A + (size_t)(row0 + r0_) * 256 + o0_ * 8;
    const float* Ap1 = A + (size_t)(row0 + r1_) * 256 + o1_ * 8;

    // ---- per-thread B-staging pointers (hoisted; step advance = 64 B imm) ----
    const int lin0 = (wave * 2 + 0) * 1024 + lane * 16;
    const int lin1 = (wave * 2 + 1) * 1024 + lane * 16;
    const char* pBh0 = (const char*)Bh + ((size_t)(col0 + (lin0 >> 6)) * 256) * 2 + (lin0 & 63);
    const char* pBl0 = (const char*)Bl + ((size_t)(col0 + (lin0 >> 6)) * 256) * 2 + (lin0 & 63);
    const char* pBh1 = (const char*)Bh + ((size_t)(col0 + (lin1 >> 6)) * 256) * 2 + (lin1 & 63);
    const char* pBl1 = (const char*)Bl + ((size_t)(col0 + (lin1 >> 6)) * 256) * 2 + (lin1 & 63);
    char* lBh0 = (char*)&Bs[0][0][0] + lin0;
    char* lBh1 = (char*)&Bs[0][0][0] + lin1;
    char* lBl0 = (char*)&Bs[1][0][0] + lin0;
    char* lBl1 = (char*)&Bs[1][0][0] + lin1;

    v4f acc[4][4] = {};

    // ---- prologue: A(0) into rotation regs ----
    float4 f00 = *(const float4*)(Ap0);
    float4 f01 = *(const float4*)(Ap0 + 4);
    float4 f10 = *(const float4*)(Ap1);
    float4 f11 = *(const float4*)(Ap1 + 4);

#pragma unroll
    for (int t = 0; t < 8; ++t) {
        // ---- barrier-1 (raw): previous step's LDS readers done ----
        asm volatile("s_waitcnt lgkmcnt(0)" ::: "memory");
        __builtin_amdgcn_s_barrier();

        // ---- B(t) async global->LDS: oldest VMEM of this step ----
        copy16_async(pBh0 + t * 64, lBh0);
        copy16_async(pBh1 + t * 64, lBh1);
        copy16_async(pBl0 + t * 64, lBl0);
        copy16_async(pBl1 + t * 64, lBl1);

        // keep all later VMEM younger than the B asyncs (vmcnt counting)
        asm volatile("" ::: "memory");
        __builtin_amdgcn_sched_barrier(0);

        // ---- split A(t) regs (the only wait point for A(t); covered by
        //      the previous step's MFMA region + barriers) ----
        unsigned hpk0[4], lpk0[4], hpk1[4], lpk1[4];
        split2(f00.x, f00.y, hpk0[0], lpk0[0]);
        split2(f00.z, f00.w, hpk0[1], lpk0[1]);
        split2(f01.x, f01.y, hpk0[2], lpk0[2]);
        split2(f01.z, f01.w, hpk0[3], lpk0[3]);
        split2(f10.x, f10.y, hpk1[0], lpk1[0]);
        split2(f10.z, f10.w, hpk1[1], lpk1[1]);
        split2(f11.x, f11.y, hpk1[2], lpk1[2]);
        split2(f11.z, f11.w, hpk1[3], lpk1[3]);

        // ---- prefetch A(t+1) into the just-freed regs (youngest VMEM) ----
        if (t < 7) {
            const int k1 = (t + 1) * 32;
            f00 = *(const float4*)(Ap0 + k1);
            f01 = *(const float4*)(Ap0 + k1 + 4);
            f10 = *(const float4*)(Ap1 + k1);
            f11 = *(const float4*)(Ap1 + k1 + 4);
        }

        // ---- A packed hi/lo -> LDS (b128, swizzled octet) ----
        *(uint4*)&Ah[r0_][oo0] = make_uint4(hpk0[0], hpk0[1], hpk0[2], hpk0[3]);
        *(uint4*)&Al[r0_][oo0] = make_uint4(lpk0[0], lpk0[1], lpk0[2], lpk0[3]);
        *(uint4*)&Ah[r1_][oo1] = make_uint4(hpk1[0], hpk1[1], hpk1[2], hpk1[3]);
        *(uint4*)&Al[r1_][oo1] = make_uint4(lpk1[0], lpk1[1], lpk1[2], lpk1[3]);

        // ---- barrier-2 (raw, counted): A writes visible + B(t) landed;
        //      A(t+1) loads stay in flight across the barrier + MFMA ----
        if (t < 7) {
            asm volatile("s_waitcnt vmcnt(4) lgkmcnt(0)" ::: "memory");
        } else {
            asm volatile("s_waitcnt vmcnt(0) lgkmcnt(0)" ::: "memory");
        }
        __builtin_amdgcn_s_barrier();

        // ---- fragments (loop-invariant LDS addresses) + MFMA ----
#pragma unroll
        for (int i = 0; i < 4; ++i) {
            const int r  = wm + i * 16 + m16;
            const int ka = (quad ^ ((r >> 1) & 3)) << 3;
            const v8s ah = *(v8s*)&Ah[r][ka];
            const v8s al = *(v8s*)&Al[r][ka];
#pragma unroll
            for (int j = 0; j < 4; ++j) {
                const int n  = wn + j * 16 + m16;
                const int ko = (quad ^ ((n >> 1) & 3)) << 3;
                const v8s bh = *(v8s*)&Bs[0][n][ko];
                const v8s bl = *(v8s*)&Bs[1][n][ko];
                acc[i][j] = __builtin_amdgcn_mfma_f32_16x16x32_bf16(ah, bh, acc[i][j], 0, 0, 0);
                acc[i][j] = __builtin_amdgcn_mfma_f32_16x16x32_bf16(ah, bl, acc[i][j], 0, 0, 0);
                acc[i][j] = __builtin_amdgcn_mfma_f32_16x16x32_bf16(al, bh, acc[i][j], 0, 0, 0);
            }
        }
    }

    // ---- epilogue: D[row=quad*4+reg][col=lane&15] ----
#pragma unroll
    for (int j = 0; j < 4; ++j) {
        const int cl = col0 + wn + j * 16 + m16;
        const float bb = bias[cl];
        if (mode == 0) {
#pragma unroll
            for (int i = 0; i < 4; ++i)
#pragma unroll
                for (int r = 0; r < 4; ++r) {
                    const int R = row0 + wm + i * 16 + quad * 4 + r;
                    Cf[(size_t)R * ldc + cl] = acc[i][j][r] + bb;
                }
        } else {
            const int h  = cl >> 5;
            const int dh = cl & 31;
#pragma unroll
            for (int i = 0; i < 4; ++i)
#pragma unroll
                for (int r = 0; r < 4; ++r) {
                    const int R = row0 + wm + i * 16 + quad * 4 + r;
                    const unsigned b = (unsigned)R / V_TOT;
                    const int v = R - (int)b * V_TOT;
                    Cb[(((size_t)(b * NH + h)) * V_TOT + v) * HD + dh] =
                        f2bf_rne(acc[i][j][r] + bb);
                }
        }
    }
}

// ---------------------------------------------------------------------------
// GEMM, bf16 A (pre-swizzled rows): C = A(Mx256) @ B(256xN) + bias, f32 out.
// 2-product (A * (Bhi+Blo)). All operands async-staged, 2-phase pipelined,
// one barrier per K-step.
// ---------------------------------------------------------------------------
__global__ __launch_bounds__(256) void gemm_a16(
    const unsigned short* __restrict__ A,     // [M][256] bf16, swizzled octets
    const unsigned short* __restrict__ Bh,
    const unsigned short* __restrict__ Bl,
    const float* __restrict__ bias,
    float* __restrict__ C, int ldc)
{
    __shared__ unsigned short As[2][128][32];
    __shared__ unsigned short Bs[2][2][128][32];

    const int tid  = threadIdx.x;
    const int row0 = blockIdx.x * 128;
    const int col0 = blockIdx.y * 128;
    const int wave = tid >> 6;
    const int lane = tid & 63;
    const int wm   = (wave >> 1) * 64;
    const int wn   = (wave & 1) * 64;
    const int m16  = lane & 15;
    const int quad = lane >> 4;

    v4f acc[4][4] = {};

    // prologue: stage K-step 0 into buffer 0
#pragma unroll
    for (int c = 0; c < 2; ++c) {
        const int linear = (wave * 2 + c) * 1024 + lane * 16;
        const int n   = linear >> 6;
        const int off = linear & 63;
        copy16_async((const char*)A  + ((size_t)(row0 + n) * 256 + 0) * 2 + off,
                     (char*)&As[0][0][0] + linear);
        copy16_async((const char*)Bh + ((size_t)(col0 + n) * 256 + 0) * 2 + off,
                     (char*)&Bs[0][0][0][0] + linear);
        copy16_async((const char*)Bl + ((size_t)(col0 + n) * 256 + 0) * 2 + off,
                     (char*)&Bs[0][1][0][0] + linear);
    }
    __syncthreads();

    for (int t = 0; t < 8; ++t) {
        const int buf = t & 1;
        const int nb  = buf ^ 1;
        const int k1  = (t + 1) << 5;

        if (t < 7) {
#pragma unroll
            for (int c = 0; c < 2; ++c) {
                const int linear = (wave * 2 + c) * 1024 + lane * 16;
                const int n   = linear >> 6;
                const int off = linear & 63;
                copy16_async((const char*)A  + ((size_t)(row0 + n) * 256 + k1) * 2 + off,
                             (char*)&As[nb][0][0] + linear);
                copy16_async((const char*)Bh + ((size_t)(col0 + n) * 256 + k1) * 2 + off,
                             (char*)&Bs[nb][0][0][0] + linear);
                copy16_async((const char*)Bl + ((size_t)(col0 + n) * 256 + k1) * 2 + off,
                             (char*)&Bs[nb][1][0][0] + linear);
            }
        }

        v8s a[4], bh[4], bl[4];
#pragma unroll
        for (int i = 0; i < 4; ++i) {
            const int r  = wm + i * 16 + m16;
            const int ka = (quad ^ ((r >> 1) & 3)) << 3;
            a[i] = *(v8s*)&As[buf][r][ka];
            const int n  = wn + i * 16 + m16;
            const int kb = (quad ^ ((n >> 1) & 3)) << 3;
            bh[i] = *(v8s*)&Bs[buf][0][n][kb];
            bl[i] = *(v8s*)&Bs[buf][1][n][kb];
        }
#pragma unroll
        for (int i = 0; i < 4; ++i)
#pragma unroll
            for (int j = 0; j < 4; ++j) {
                acc[i][j] = __builtin_amdgcn_mfma_f32_16x16x32_bf16(a[i], bh[j], acc[i][j], 0, 0, 0);
                acc[i][j] = __builtin_amdgcn_mfma_f32_16x16x32_bf16(a[i], bl[j], acc[i][j], 0, 0, 0);
            }

        __syncthreads();
    }

#pragma unroll
    for (int j = 0; j < 4; ++j) {
        const int cl = col0 + wn + j * 16 + m16;
        const float bb = bias[cl];
#pragma unroll
        for (int i = 0; i < 4; ++i)
#pragma unroll
            for (int r = 0; r < 4; ++r) {
                const int R = row0 + wm + i * 16 + quad * 4 + r;
                C[(size_t)R * ldc + cl] = acc[i][j][r] + bb;
            }
    }
}

// ---------------------------------------------------------------------------
// Sampler v2: softmax(16) + bilinear gather + weighted sum.
// Changes vs v1 (first optimization pass on this kernel):
//  * POINT-SPLIT x2 TLP: thread = (bq, half, h, d8); each thread does 2
//    levels (8 points, 32 corners) instead of 4; waves/SIMD ~4.7 -> ~9.4
//    for gather-latency hiding. Partial sums combined with one
//    __shfl_xor(acc,32) (half = lane bit 5; exact pairwise re-assoc).
//  * XCD-CHUNK SWIZZLE: swz=(g&7)*300+g/8 (2400%8==0, bijective). Each
//    XCD gets a contiguous bq range -> one b's val slice (4.35 MB) at a
//    time resident in its 4 MB L2 instead of all-XCD L3 scatter.
//  * Rule #20 audit: runtime level l never indexes a local array —
//    aw[] accessed via half-ternary with compile-time indices.
// 4 lanes (d8=0..3) with same (bq,half,h) still read one contiguous 64B
// line per corner. Output pre bf16 with GEMM octet swizzle (half==0 writes).
// ---------------------------------------------------------------------------
__global__ __launch_bounds__(256) void sample_kernel(
    const float* __restrict__ refp,
    const float* __restrict__ offattn,            // [9600][384]
    const unsigned short* __restrict__ val,       // [b][h][V][32] bf16
    unsigned short* __restrict__ pre)             // [9600][256] bf16 swizzled
{
    const int g  = blockIdx.x;                      // 0..2399
    const int sb = (g & 7) * 300 + (g >> 3);        // XCD-chunk swizzle
    const int t  = sb * 256 + threadIdx.x;          // 0 .. 614399
    const int d8   = t & 3;
    const int h    = (t >> 2) & 7;
    const int half = (t >> 5) & 1;                  // lane bit 5
    const int bq   = t >> 6;
    const int b    = bq / NQ;

    const float* rp = refp + (size_t)bq * 8;
    const float* op = offattn + (size_t)bq * 384 + h * 32;
    const float* ap = offattn + (size_t)bq * 384 + 256 + h * 16;

    // softmax over the 16 (l,p) logits (all threads; normalization needs all)
    float aw[16];
    float m = -1e30f;
#pragma unroll
    for (int i = 0; i < 16; ++i) { aw[i] = ap[i]; m = fmaxf(m, aw[i]); }
    float s = 0.f;
#pragma unroll
    for (int i = 0; i < 16; ++i) { aw[i] = __expf(aw[i] - m); s += aw[i]; }
    const float inv = 1.f / s;
#pragma unroll
    for (int i = 0; i < 16; ++i) aw[i] *= inv;

    float acc[8] = {};
#pragma unroll
    for (int li = 0; li < 2; ++li) {
        // l = half*2 + li; all level-dependent constants via half-ternary
        const int Wl = li ? (half ? 10 : 40) : (half ? 20 : 80);
        const int St = li ? (half ? 8400 : 6400) : (half ? 8000 : 0);
        const int l2 = (half ? 2 : 0) + li;          // for global-ptr offsets
        const float fW = (float)Wl, fH = (float)Wl;
        const float rx = rp[l2 * 2 + 0];
        const float ry = rp[l2 * 2 + 1];
        const unsigned short* vb =
            val + (((size_t)(b * NH + h)) * V_TOT + St) * HD + d8 * 8;
#pragma unroll
        for (int p = 0; p < NP; ++p) {
            const float ox = op[l2 * 8 + p * 2 + 0];
            const float oy = op[l2 * 8 + p * 2 + 1];
            const float w  = half ? aw[8 + li * 4 + p] : aw[li * 4 + p];
            const float x = fmaf(rx, fW, ox) - 0.5f;
            const float y = fmaf(ry, fH, oy) - 0.5f;
            const float x0f = floorf(x), y0f = floorf(y);
            const int   x0 = (int)x0f,  y0 = (int)y0f;
            const float wx1 = x - x0f,  wy1 = y - y0f;
            const float wx0 = 1.f - wx1, wy0 = 1.f - wy1;
#pragma unroll
            for (int cy = 0; cy < 2; ++cy) {
#pragma unroll
                for (int cx = 0; cx < 2; ++cx) {
                    const int xi = x0 + cx;
                    const int yi = y0 + cy;
                    float cw = (cx ? wx1 : wx0) * (cy ? wy1 : wy0) * w;
                    const bool valid = (xi >= 0) && (xi < Wl) && (yi >= 0) && (yi < Wl);
                    cw = valid ? cw : 0.f;
                    const int xc = xi < 0 ? 0 : (xi > Wl - 1 ? Wl - 1 : xi);
                    const int yc = yi < 0 ? 0 : (yi > Wl - 1 ? Wl - 1 : yi);
                    const uint4 gld = *(const uint4*)(vb + (size_t)(yc * Wl + xc) * HD);
                    const unsigned gu[4] = {gld.x, gld.y, gld.z, gld.w};
#pragma unroll
                    for (int e = 0; e < 4; ++e) {
                        acc[2*e]   = fmaf(cw, __uint_as_float(gu[e] << 16),        acc[2*e]);
                        acc[2*e+1] = fmaf(cw, __uint_as_float(gu[e] & 0xffff0000u), acc[2*e+1]);
                    }
                }
            }
        }
    }

    // combine the two level-halves (partner lane = lane ^ 32)
#pragma unroll
    for (int e = 0; e < 8; ++e) acc[e] += __shfl_xor(acc[e], 32);

    if (half == 0) {
        unsigned o[4];
#pragma unroll
        for (int e = 0; e < 4; ++e)
            o[e] = (unsigned)f2bf_rne(acc[2*e]) | ((unsigned)f2bf_rne(acc[2*e+1]) << 16);
        const int octswz = d8 ^ ((bq >> 1) & 3);
        *(uint4*)(pre + (size_t)bq * 256 + h * 32 + octswz * 8) =
            make_uint4(o[0], o[1], o[2], o[3]);
    }
}

// ---------------------------------------------------------------------------
extern "C" void kernel_launch(void* const* d_in, const int* in_sizes, int n_in,
                              void* d_out, int out_size, void* d_ws, size_t ws_size,
                              hipStream_t stream)
{
    const float* query  = (const float*)d_in[0];
    const float* refp   = (const float*)d_in[1];
    const float* value  = (const float*)d_in[2];
    const float* W_off  = (const float*)d_in[5];
    const float* b_off  = (const float*)d_in[6];
    const float* W_attn = (const float*)d_in[7];
    const float* b_attn = (const float*)d_in[8];
    const float* W_val  = (const float*)d_in[9];
    const float* b_val  = (const float*)d_in[10];
    const float* W_out  = (const float*)d_in[11];
    const float* b_out  = (const float*)d_in[12];
    float* out = (float*)d_out;

    char* ws = (char*)d_ws;
    unsigned short* val     = (unsigned short*)ws;                       // 139,264,000 B
    float*          offattn = (float*)(ws + 139264000);                  // 14,745,600 B
    unsigned short* pre     = (unsigned short*)(ws + 154009600);         //  4,915,200 B
    unsigned short* Bval_h  = (unsigned short*)(ws + 158924800);         //    131,072 B
    unsigned short* Bval_l  = Bval_h + 65536;
    unsigned short* Boa_h   = Bval_l + 65536;                            //    196,608 B
    unsigned short* Boa_l   = Boa_h + 98304;
    unsigned short* Bout_h  = Boa_l + 98304;
    unsigned short* Bout_l  = Bout_h + 65536;
    float*          b_oa    = (float*)(Bout_l + 65536);

    const dim3 blk(256);

    // 0) weight prep: transpose + RNE hi/lo split + swizzle + bias concat
    prep_weights<<<dim3(898), blk, 0, stream>>>(
        W_val, W_off, W_attn, W_out, b_off, b_attn,
        Bval_h, Bval_l, Boa_h, Boa_l, Bout_h, Bout_l, b_oa);

    // 1) val = value @ W_val + b_val -> bf16 [b][h][V][hd]   (grid: x=Ntile)
    gemm_a32<<<dim3(2, MVAL / 128), blk, 0, stream>>>(
        value, Bval_h, Bval_l, b_val, nullptr, val, 0, 1);

    // 2) fused off+attn projection -> f32 [9600][384]
    gemm_a32<<<dim3(3, BQ_TOT / 128), blk, 0, stream>>>(
        query, Boa_h, Boa_l, b_oa, offattn, nullptr, NOA, 0);

    // 3) softmax + bilinear sampling + weighted sum -> pre bf16 (swizzled)
    //    2x point-split TLP + XCD-chunk swizzle
    sample_kernel<<<dim3((BQ_TOT * 64) / 256), blk, 0, stream>>>(
        refp, offattn, val, pre);

    // 4) out = pre @ W_out + b_out -> f32 [9600][256]
    gemm_a16<<<dim3(BQ_TOT / 128, 2), blk, 0, stream>>>(
        pre, Bout_h, Bout_l, b_out, out, 256);
}

// Round 10
// 528.812 us; speedup vs baseline: 1.7671x; 1.0047x over previous
//
#include <hip/hip_runtime.h>
#include <hip/hip_bf16.h>
#include <math.h>
#include <stdint.h>

// Problem constants (deterministic from setup_inputs)
#define NB 32
#define NQ 300
#define ND 256
#define NH 8
#define HD 32
#define NL 4
#define NP 4
#define V_TOT 8500           // 6400+1600+400+100
#define BQ_TOT (NB*NQ)       // 9600
#define MVAL (NB*V_TOT)      // 272000
#define NOA 384              // fused off(256)+attn(128) cols

typedef short v8s __attribute__((ext_vector_type(8)));
typedef float v4f __attribute__((ext_vector_type(4)));

#define AS1 __attribute__((address_space(1)))
#define AS3 __attribute__((address_space(3)))

__device__ __forceinline__ void copy16_async(const void* g, void* l) {
#if __has_builtin(__builtin_amdgcn_global_load_lds)
    __builtin_amdgcn_global_load_lds((const AS1 unsigned int*)g,
                                     (AS3 unsigned int*)l, 16, 0, 0);
#else
    *(uint4*)l = *(const uint4*)g;
#endif
}

__device__ __forceinline__ unsigned short f2bf_rne(float x) {
    unsigned u = __float_as_uint(x);
    u += 0x7fffu + ((u >> 16) & 1u);
    return (unsigned short)(u >> 16);
}
__device__ __forceinline__ float bf2f(unsigned short b) {
    return __uint_as_float(((unsigned)b) << 16);
}

// RNE hi/lo split of an f32 pair into two packed-bf16 words using the
// packed convert (v_cvt_pk_bf16_f32). lo = x - hi is exact.
__device__ __forceinline__ void split2(float f0, float f1,
                                       unsigned& hp, unsigned& lp) {
    float2 v; v.x = f0; v.y = f1;
    __hip_bfloat162 h = __float22bfloat162_rn(v);
    unsigned hu; __builtin_memcpy(&hu, &h, 4);
    const float h0 = __uint_as_float(hu << 16);
    const float h1 = __uint_as_float(hu & 0xffff0000u);
    float2 l; l.x = f0 - h0; l.y = f1 - h1;
    __hip_bfloat162 lo = __float22bfloat162_rn(l);
    unsigned lu; __builtin_memcpy(&lu, &lo, 4);
    hp = hu; lp = lu;
}

// Swizzled flat position of element (n,k) in a prepped [N][256] bf16 array.
// Within each 32-k tile the 4 octets (8 els) are XOR-permuted by ((n>>1)&3)
// -> fragment reads spread across all 32 banks (0 conflicts, measured r3).
__device__ __forceinline__ int swz_pos(int n, int k) {
    const int base = k & ~31;
    const int o = (k >> 3) & 3;
    const int op = o ^ ((n >> 1) & 3);
    return n * 256 + base + (op << 3) + (k & 7);
}

// ---------------------------------------------------------------------------
// Prep: transpose + hi/lo-split (RNE) all three weight matrices into
// n-major swizzled bf16; concat biases for the fused off/attn projection.
// ---------------------------------------------------------------------------
__global__ __launch_bounds__(256) void prep_weights(
    const float* __restrict__ W_val, const float* __restrict__ W_off,
    const float* __restrict__ W_attn, const float* __restrict__ W_out,
    const float* __restrict__ b_off, const float* __restrict__ b_attn,
    unsigned short* __restrict__ Bval_h, unsigned short* __restrict__ Bval_l,
    unsigned short* __restrict__ Boa_h,  unsigned short* __restrict__ Boa_l,
    unsigned short* __restrict__ Bout_h, unsigned short* __restrict__ Bout_l,
    float* __restrict__ b_oa)
{
    const int t = blockIdx.x * 256 + threadIdx.x;
    if (t < 65536) {
        const int n = t >> 8, k = t & 255;
        const float x = W_val[k * 256 + n];
        const unsigned short hi = f2bf_rne(x);
        const unsigned short lo = f2bf_rne(x - bf2f(hi));
        const int p = swz_pos(n, k);
        Bval_h[p] = hi; Bval_l[p] = lo;
    } else if (t < 65536 + 98304) {
        const int t2 = t - 65536;
        const int n = t2 >> 8, k = t2 & 255;
        const float x = (n < 256) ? W_off[k * 256 + n] : W_attn[k * 128 + (n - 256)];
        const unsigned short hi = f2bf_rne(x);
        const unsigned short lo = f2bf_rne(x - bf2f(hi));
        const int p = swz_pos(n, k);
        Boa_h[p] = hi; Boa_l[p] = lo;
    } else if (t < 229376) {
        const int t3 = t - 163840;
        const int n = t3 >> 8, k = t3 & 255;
        const float x = W_out[k * 256 + n];
        const unsigned short hi = f2bf_rne(x);
        const unsigned short lo = f2bf_rne(x - bf2f(hi));
        const int p = swz_pos(n, k);
        Bout_h[p] = hi; Bout_l[p] = lo;
    } else {
        const int t4 = t - 229376;
        if (t4 < NOA) b_oa[t4] = (t4 < 256) ? b_off[t4] : b_attn[t4 - 256];
    }
}

// ---------------------------------------------------------------------------
// GEMM, f32 A: C = A(Mx256) @ B(256xN) + bias, bf16-split 3-product MFMA.
// r9 schedule + B LDS DOUBLE-BUFFER (early B issue):
//  * B(t+1) is issued at the TOP of step t into buf^1 (one full step of
//    latency cover). split(t)'s compiler-inserted wait for the A(t) regs
//    (queue: [B(t)x4, A(t)x4, B(t+1)x4], wait <= vmcnt(4)) forces B(t)
//    as a side effect -> B never stalls the barrier.
//  * barrier-2: vmcnt(8) lgkmcnt(0) -> the 8 outstanding ops are exactly
//    B(t+1)+A(t+1); NO memory wait remains on the barrier beyond the
//    trivial lgkm of this wave's 4 ds_writes. vmcnt(0) at t=7 (tail).
//  * A 1-deep register rotation unchanged (r5-proven; 2-deep closed r6-r8).
// Hazard ledger: Bs[buf^1] write at t vs Bs[buf] read at t disjoint;
// buf^1's previous readers fenced by barrier-1 (lgkm+s_barrier); each wave
// forces its own B(t) slice at its split before crossing barrier-2; A ds
// writes visible via lgkm at barrier-2; issue-order B(t+1) < A(t+1) pinned
// by fence + sched_barrier(0). LDS 48 KB -> still 3 blocks/CU.
// mode 0: Cf row-major [M][ldc] f32.
// mode 1: Cb = bf16 val layout C[((b*NH+h)*V_TOT+v)*HD+dh], row=(b,v), col=(h,dh)
// ---------------------------------------------------------------------------
__global__ __launch_bounds__(256, 3) void gemm_a32(
    const float* __restrict__ A,
    const unsigned short* __restrict__ Bh,
    const unsigned short* __restrict__ Bl,
    const float* __restrict__ bias,
    float* __restrict__ Cf,
    unsigned short* __restrict__ Cb,
    int ldc, int mode)
{
    __shared__ unsigned short Ah[128][32];        // octet-XOR swizzled
    __shared__ unsigned short Al[128][32];
    __shared__ unsigned short Bs[2][2][128][32];  // [buf][hi/lo], swizzled

    const int tid  = threadIdx.x;
    const int col0 = blockIdx.x * 128;            // N-tile (fast axis)
    const int row0 = blockIdx.y * 128;            // M-tile
    const int wave = tid >> 6;
    const int lane = tid & 63;
    const int wm   = (wave >> 1) * 64;
    const int wn   = (wave & 1) * 64;
    const int m16  = lane & 15;
    const int quad = lane >> 4;

    // ---- per-thread A-staging coords (2 quarter-rows of 8 f32) ----
    const int i0  = tid;
    const int i1  = tid + 256;
    const int r0_ = i0 >> 2, o0_ = i0 & 3;
    const int r1_ = i1 >> 2, o1_ = i1 & 3;
    const int oo0 = (o0_ ^ ((r0_ >> 1) & 3)) << 3;   // swizzled LDS elem offset
    const int oo1 = (o1_ ^ ((r1_ >> 1) & 3)) << 3;
    const float* Ap0 = A + (size_t)(row0 + r0_) * 256 + o0_ * 8;
    const float* Ap1 = A + (size_t)(row0 + r1_) * 256 + o1_ * 8;

    // ---- per-thread B-staging pointers (hoisted; step advance = 64 B imm) ----
    const int lin0 = (wave * 2 + 0) * 1024 + lane * 16;
    const int lin1 = (wave * 2 + 1) * 1024 + lane * 16;
    const char* pBh0 = (const char*)Bh + ((size_t)(col0 + (lin0 >> 6)) * 256) * 2 + (lin0 & 63);
    const char* pBl0 = (const char*)Bl + ((size_t)(col0 + (lin0 >> 6)) * 256) * 2 + (lin0 & 63);
    const char* pBh1 = (const char*)Bh + ((size_t)(col0 + (lin1 >> 6)) * 256) * 2 + (lin1 & 63);
    const char* pBl1 = (const char*)Bl + ((size_t)(col0 + (lin1 >> 6)) * 256) * 2 + (lin1 & 63);

    v4f acc[4][4] = {};

    // ---- prologue: B(0) asyncs -> buf0 (oldest), then A(0) -> regs ----
    copy16_async(pBh0, (char*)&Bs[0][0][0][0] + lin0);
    copy16_async(pBh1, (char*)&Bs[0][0][0][0] + lin1);
    copy16_async(pBl0, (char*)&Bs[0][1][0][0] + lin0);
    copy16_async(pBl1, (char*)&Bs[0][1][0][0] + lin1);
    asm volatile("" ::: "memory");
    __builtin_amdgcn_sched_barrier(0);
    float4 f00 = *(const float4*)(Ap0);
    float4 f01 = *(const float4*)(Ap0 + 4);
    float4 f10 = *(const float4*)(Ap1);
    float4 f11 = *(const float4*)(Ap1 + 4);

#pragma unroll
    for (int t = 0; t < 8; ++t) {
        const int buf = t & 1;                    // compile-time (full unroll)

        // ---- barrier-1 (raw): previous step's LDS readers done ----
        asm volatile("s_waitcnt lgkmcnt(0)" ::: "memory");
        __builtin_amdgcn_s_barrier();

        // ---- issue B(t+1) -> buf^1 (oldest VMEM of this step) ----
        if (t < 7) {
            const int nb = buf ^ 1;
            copy16_async(pBh0 + (t + 1) * 64, (char*)&Bs[nb][0][0][0] + lin0);
            copy16_async(pBh1 + (t + 1) * 64, (char*)&Bs[nb][0][0][0] + lin1);
            copy16_async(pBl0 + (t + 1) * 64, (char*)&Bs[nb][1][0][0] + lin0);
            copy16_async(pBl1 + (t + 1) * 64, (char*)&Bs[nb][1][0][0] + lin1);
        }

        // pin issue order: B(t+1) older than everything below
        asm volatile("" ::: "memory");
        __builtin_amdgcn_sched_barrier(0);

        // ---- split A(t): the implicit wait on A(t) regs (<= vmcnt(4))
        //      also forces B(t), both with ~a full step of cover ----
        unsigned hpk0[4], lpk0[4], hpk1[4], lpk1[4];
        split2(f00.x, f00.y, hpk0[0], lpk0[0]);
        split2(f00.z, f00.w, hpk0[1], lpk0[1]);
        split2(f01.x, f01.y, hpk0[2], lpk0[2]);
        split2(f01.z, f01.w, hpk0[3], lpk0[3]);
        split2(f10.x, f10.y, hpk1[0], lpk1[0]);
        split2(f10.z, f10.w, hpk1[1], lpk1[1]);
        split2(f11.x, f11.y, hpk1[2], lpk1[2]);
        split2(f11.z, f11.w, hpk1[3], lpk1[3]);

        // ---- prefetch A(t+1) into the just-freed regs (youngest VMEM) ----
        if (t < 7) {
            const int k1 = (t + 1) * 32;
            f00 = *(const float4*)(Ap0 + k1);
            f01 = *(const float4*)(Ap0 + k1 + 4);
            f10 = *(const float4*)(Ap1 + k1);
            f11 = *(const float4*)(Ap1 + k1 + 4);
        }

        // ---- A packed hi/lo -> LDS (b128, swizzled octet) ----
        *(uint4*)&Ah[r0_][oo0] = make_uint4(hpk0[0], hpk0[1], hpk0[2], hpk0[3]);
        *(uint4*)&Al[r0_][oo0] = make_uint4(lpk0[0], lpk0[1], lpk0[2], lpk0[3]);
        *(uint4*)&Ah[r1_][oo1] = make_uint4(hpk1[0], hpk1[1], hpk1[2], hpk1[3]);
        *(uint4*)&Al[r1_][oo1] = make_uint4(lpk1[0], lpk1[1], lpk1[2], lpk1[3]);

        // ---- barrier-2 (raw, counted): only next-step VMEM outstanding
        //      (B(t+1)x4 + A(t+1)x4 = 8); lgkm flushes A ds_writes ----
        if (t < 7) {
            asm volatile("s_waitcnt vmcnt(8) lgkmcnt(0)" ::: "memory");
        } else {
            asm volatile("s_waitcnt vmcnt(0) lgkmcnt(0)" ::: "memory");
        }
        __builtin_amdgcn_s_barrier();

        // ---- fragments (loop-invariant LDS addresses) + MFMA ----
#pragma unroll
        for (int i = 0; i < 4; ++i) {
            const int r  = wm + i * 16 + m16;
            const int ka = (quad ^ ((r >> 1) & 3)) << 3;
            const v8s ah = *(v8s*)&Ah[r][ka];
            const v8s al = *(v8s*)&Al[r][ka];
#pragma unroll
            for (int j = 0; j < 4; ++j) {
                const int n  = wn + j * 16 + m16;
                const int ko = (quad ^ ((n >> 1) & 3)) << 3;
                const v8s bh = *(v8s*)&Bs[buf][0][n][ko];
                const v8s bl = *(v8s*)&Bs[buf][1][n][ko];
                acc[i][j] = __builtin_amdgcn_mfma_f32_16x16x32_bf16(ah, bh, acc[i][j], 0, 0, 0);
                acc[i][j] = __builtin_amdgcn_mfma_f32_16x16x32_bf16(ah, bl, acc[i][j], 0, 0, 0);
                acc[i][j] = __builtin_amdgcn_mfma_f32_16x16x32_bf16(al, bh, acc[i][j], 0, 0, 0);
            }
        }
    }

    // ---- epilogue: D[row=quad*4+reg][col=lane&15] ----
#pragma unroll
    for (int j = 0; j < 4; ++j) {
        const int cl = col0 + wn + j * 16 + m16;
        const float bb = bias[cl];
        if (mode == 0) {
#pragma unroll
            for (int i = 0; i < 4; ++i)
#pragma unroll
                for (int r = 0; r < 4; ++r) {
                    const int R = row0 + wm + i * 16 + quad * 4 + r;
                    Cf[(size_t)R * ldc + cl] = acc[i][j][r] + bb;
                }
        } else {
            const int h  = cl >> 5;
            const int dh = cl & 31;
#pragma unroll
            for (int i = 0; i < 4; ++i)
#pragma unroll
                for (int r = 0; r < 4; ++r) {
                    const int R = row0 + wm + i * 16 + quad * 4 + r;
                    const unsigned b = (unsigned)R / V_TOT;
                    const int v = R - (int)b * V_TOT;
                    Cb[(((size_t)(b * NH + h)) * V_TOT + v) * HD + dh] =
                        f2bf_rne(acc[i][j][r] + bb);
                }
        }
    }
}

// ---------------------------------------------------------------------------
// GEMM, bf16 A (pre-swizzled rows): C = A(Mx256) @ B(256xN) + bias, f32 out.
// 2-product (A * (Bhi+Blo)). All operands async-staged, 2-phase pipelined,
// one barrier per K-step.
// ---------------------------------------------------------------------------
__global__ __launch_bounds__(256) void gemm_a16(
    const unsigned short* __restrict__ A,     // [M][256] bf16, swizzled octets
    const unsigned short* __restrict__ Bh,
    const unsigned short* __restrict__ Bl,
    const float* __restrict__ bias,
    float* __restrict__ C, int ldc)
{
    __shared__ unsigned short As[2][128][32];
    __shared__ unsigned short Bs[2][2][128][32];

    const int tid  = threadIdx.x;
    const int row0 = blockIdx.x * 128;
    const int col0 = blockIdx.y * 128;
    const int wave = tid >> 6;
    const int lane = tid & 63;
    const int wm   = (wave >> 1) * 64;
    const int wn   = (wave & 1) * 64;
    const int m16  = lane & 15;
    const int quad = lane >> 4;

    v4f acc[4][4] = {};

    // prologue: stage K-step 0 into buffer 0
#pragma unroll
    for (int c = 0; c < 2; ++c) {
        const int linear = (wave * 2 + c) * 1024 + lane * 16;
        const int n   = linear >> 6;
        const int off = linear & 63;
        copy16_async((const char*)A  + ((size_t)(row0 + n) * 256 + 0) * 2 + off,
                     (char*)&As[0][0][0] + linear);
        copy16_async((const char*)Bh + ((size_t)(col0 + n) * 256 + 0) * 2 + off,
                     (char*)&Bs[0][0][0][0] + linear);
        copy16_async((const char*)Bl + ((size_t)(col0 + n) * 256 + 0) * 2 + off,
                     (char*)&Bs[0][1][0][0] + linear);
    }
    __syncthreads();

    for (int t = 0; t < 8; ++t) {
        const int buf = t & 1;
        const int nb  = buf ^ 1;
        const int k1  = (t + 1) << 5;

        if (t < 7) {
#pragma unroll
            for (int c = 0; c < 2; ++c) {
                const int linear = (wave * 2 + c) * 1024 + lane * 16;
                const int n   = linear >> 6;
                const int off = linear & 63;
                copy16_async((const char*)A  + ((size_t)(row0 + n) * 256 + k1) * 2 + off,
                             (char*)&As[nb][0][0] + linear);
                copy16_async((const char*)Bh + ((size_t)(col0 + n) * 256 + k1) * 2 + off,
                             (char*)&Bs[nb][0][0][0] + linear);
                copy16_async((const char*)Bl + ((size_t)(col0 + n) * 256 + k1) * 2 + off,
                             (char*)&Bs[nb][1][0][0] + linear);
            }
        }

        v8s a[4], bh[4], bl[4];
#pragma unroll
        for (int i = 0; i < 4; ++i) {
            const int r  = wm + i * 16 + m16;
            const int ka = (quad ^ ((r >> 1) & 3)) << 3;
            a[i] = *(v8s*)&As[buf][r][ka];
            const int n  = wn + i * 16 + m16;
            const int kb = (quad ^ ((n >> 1) & 3)) << 3;
            bh[i] = *(v8s*)&Bs[buf][0][n][kb];
            bl[i] = *(v8s*)&Bs[buf][1][n][kb];
        }
#pragma unroll
        for (int i = 0; i < 4; ++i)
#pragma unroll
            for (int j = 0; j < 4; ++j) {
                acc[i][j] = __builtin_amdgcn_mfma_f32_16x16x32_bf16(a[i], bh[j], acc[i][j], 0, 0, 0);
                acc[i][j] = __builtin_amdgcn_mfma_f32_16x16x32_bf16(a[i], bl[j], acc[i][j], 0, 0, 0);
            }

        __syncthreads();
    }

#pragma unroll
    for (int j = 0; j < 4; ++j) {
        const int cl = col0 + wn + j * 16 + m16;
        const float bb = bias[cl];
#pragma unroll
        for (int i = 0; i < 4; ++i)
#pragma unroll
            for (int r = 0; r < 4; ++r) {
                const int R = row0 + wm + i * 16 + quad * 4 + r;
                C[(size_t)R * ldc + cl] = acc[i][j][r] + bb;
            }
    }
}

// ---------------------------------------------------------------------------
// Sampler v2: softmax(16) + bilinear gather + weighted sum.
//  * POINT-SPLIT x2 TLP: thread = (bq, half, h, d8); partial sums combined
//    with one __shfl_xor(acc,32) (half = lane bit 5).
//  * XCD-CHUNK SWIZZLE: swz=(g&7)*300+g/8 (bijective) for val L2 locality.
//  * Rule #20: aw[] accessed via half-ternary with compile-time indices.
// ---------------------------------------------------------------------------
__global__ __launch_bounds__(256) void sample_kernel(
    const float* __restrict__ refp,
    const float* __restrict__ offattn,            // [9600][384]
    const unsigned short* __restrict__ val,       // [b][h][V][32] bf16
    unsigned short* __restrict__ pre)             // [9600][256] bf16 swizzled
{
    const int g  = blockIdx.x;                      // 0..2399
    const int sb = (g & 7) * 300 + (g >> 3);        // XCD-chunk swizzle
    const int t  = sb * 256 + threadIdx.x;          // 0 .. 614399
    const int d8   = t & 3;
    const int h    = (t >> 2) & 7;
    const int half = (t >> 5) & 1;                  // lane bit 5
    const int bq   = t >> 6;
    const int b    = bq / NQ;

    const float* rp = refp + (size_t)bq * 8;
    const float* op = offattn + (size_t)bq * 384 + h * 32;
    const float* ap = offattn + (size_t)bq * 384 + 256 + h * 16;

    // softmax over the 16 (l,p) logits (all threads; normalization needs all)
    float aw[16];
    float m = -1e30f;
#pragma unroll
    for (int i = 0; i < 16; ++i) { aw[i] = ap[i]; m = fmaxf(m, aw[i]); }
    float s = 0.f;
#pragma unroll
    for (int i = 0; i < 16; ++i) { aw[i] = __expf(aw[i] - m); s += aw[i]; }
    const float inv = 1.f / s;
#pragma unroll
    for (int i = 0; i < 16; ++i) aw[i] *= inv;

    float acc[8] = {};
#pragma unroll
    for (int li = 0; li < 2; ++li) {
        // l = half*2 + li; all level-dependent constants via half-ternary
        const int Wl = li ? (half ? 10 : 40) : (half ? 20 : 80);
        const int St = li ? (half ? 8400 : 6400) : (half ? 8000 : 0);
        const int l2 = (half ? 2 : 0) + li;          // for global-ptr offsets
        const float fW = (float)Wl, fH = (float)Wl;
        const float rx = rp[l2 * 2 + 0];
        const float ry = rp[l2 * 2 + 1];
        const unsigned short* vb =
            val + (((size_t)(b * NH + h)) * V_TOT + St) * HD + d8 * 8;
#pragma unroll
        for (int p = 0; p < NP; ++p) {
            const float ox = op[l2 * 8 + p * 2 + 0];
            const float oy = op[l2 * 8 + p * 2 + 1];
            const float w  = half ? aw[8 + li * 4 + p] : aw[li * 4 + p];
            const float x = fmaf(rx, fW, ox) - 0.5f;
            const float y = fmaf(ry, fH, oy) - 0.5f;
            const float x0f = floorf(x), y0f = floorf(y);
            const int   x0 = (int)x0f,  y0 = (int)y0f;
            const float wx1 = x - x0f,  wy1 = y - y0f;
            const float wx0 = 1.f - wx1, wy0 = 1.f - wy1;
#pragma unroll
            for (int cy = 0; cy < 2; ++cy) {
#pragma unroll
                for (int cx = 0; cx < 2; ++cx) {
                    const int xi = x0 + cx;
                    const int yi = y0 + cy;
                    float cw = (cx ? wx1 : wx0) * (cy ? wy1 : wy0) * w;
                    const bool valid = (xi >= 0) && (xi < Wl) && (yi >= 0) && (yi < Wl);
                    cw = valid ? cw : 0.f;
                    const int xc = xi < 0 ? 0 : (xi > Wl - 1 ? Wl - 1 : xi);
                    const int yc = yi < 0 ? 0 : (yi > Wl - 1 ? Wl - 1 : yi);
                    const uint4 gld = *(const uint4*)(vb + (size_t)(yc * Wl + xc) * HD);
                    const unsigned gu[4] = {gld.x, gld.y, gld.z, gld.w};
#pragma unroll
                    for (int e = 0; e < 4; ++e) {
                        acc[2*e]   = fmaf(cw, __uint_as_float(gu[e] << 16),        acc[2*e]);
                        acc[2*e+1] = fmaf(cw, __uint_as_float(gu[e] & 0xffff0000u), acc[2*e+1]);
                    }
                }
            }
        }
    }

    // combine the two level-halves (partner lane = lane ^ 32)
#pragma unroll
    for (int e = 0; e < 8; ++e) acc[e] += __shfl_xor(acc[e], 32);

    if (half == 0) {
        unsigned o[4];
#pragma unroll
        for (int e = 0; e < 4; ++e)
            o[e] = (unsigned)f2bf_rne(acc[2*e]) | ((unsigned)f2bf_rne(acc[2*e+1]) << 16);
        const int octswz = d8 ^ ((bq >> 1) & 3);
        *(uint4*)(pre + (size_t)bq * 256 + h * 32 + octswz * 8) =
            make_uint4(o[0], o[1], o[2], o[3]);
    }
}

// ---------------------------------------------------------------------------
extern "C" void kernel_launch(void* const* d_in, const int* in_sizes, int n_in,
                              void* d_out, int out_size, void* d_ws, size_t ws_size,
                              hipStream_t stream)
{
    const float* query  = (const float*)d_in[0];
    const float* refp   = (const float*)d_in[1];
    const float* value  = (const float*)d_in[2];
    const float* W_off  = (const float*)d_in[5];
    const float* b_off  = (const float*)d_in[6];
    const float* W_attn = (const float*)d_in[7];
    const float* b_attn = (const float*)d_in[8];
    const float* W_val  = (const float*)d_in[9];
    const float* b_val  = (const float*)d_in[10];
    const float* W_out  = (const float*)d_in[11];
    const float* b_out  = (const float*)d_in[12];
    float* out = (float*)d_out;

    char* ws = (char*)d_ws;
    unsigned short* val     = (unsigned short*)ws;                       // 139,264,000 B
    float*          offattn = (float*)(ws + 139264000);                  // 14,745,600 B
    unsigned short* pre     = (unsigned short*)(ws + 154009600);         //  4,915,200 B
    unsigned short* Bval_h  = (unsigned short*)(ws + 158924800);         //    131,072 B
    unsigned short* Bval_l  = Bval_h + 65536;
    unsigned short* Boa_h   = Bval_l + 65536;                            //    196,608 B
    unsigned short* Boa_l   = Boa_h + 98304;
    unsigned short* Bout_h  = Boa_l + 98304;
    unsigned short* Bout_l  = Bout_h + 65536;
    float*          b_oa    = (float*)(Bout_l + 65536);

    const dim3 blk(256);

    // 0) weight prep: transpose + RNE hi/lo split + swizzle + bias concat
    prep_weights<<<dim3(898), blk, 0, stream>>>(
        W_val, W_off, W_attn, W_out, b_off, b_attn,
        Bval_h, Bval_l, Boa_h, Boa_l, Bout_h, Bout_l, b_oa);

    // 1) val = value @ W_val + b_val -> bf16 [b][h][V][hd]   (grid: x=Ntile)
    gemm_a32<<<dim3(2, MVAL / 128), blk, 0, stream>>>(
        value, Bval_h, Bval_l, b_val, nullptr, val, 0, 1);

    // 2) fused off+attn projection -> f32 [9600][384]
    gemm_a32<<<dim3(3, BQ_TOT / 128), blk, 0, stream>>>(
        query, Boa_h, Boa_l, b_oa, offattn, nullptr, NOA, 0);

    // 3) softmax + bilinear sampling + weighted sum -> pre bf16 (swizzled)
    //    2x point-split TLP + XCD-chunk swizzle
    sample_kernel<<<dim3((BQ_TOT * 64) / 256), blk, 0, stream>>>(
        refp, offattn, val, pre);

    // 4) out = pre @ W_out + b_out -> f32 [9600][256]
    gemm_a16<<<dim3(BQ_TOT / 128, 2), blk, 0, stream>>>(
        pre, Bout_h, Bout_l, b_out, out, 256);
}